// Round 1
// baseline (1106.443 us; speedup 1.0000x reference)
//
#include <hip/hip_runtime.h>
#include <math.h>

#define FEAT_DIM   128
#define MAX_ATOMS  15
#define MAX_AA     22
#define MAX_RELPOS 32
#define L_SEQ      256
#define KG         225   // MAX_ATOMS*MAX_ATOMS
#define KF         410   // 3*128 + 26
#define TM         16    // pairs (j's) per block

struct F3 { float x, y, z; };
__device__ inline F3 f3sub(F3 a, F3 b) { return {a.x-b.x, a.y-b.y, a.z-b.z}; }
__device__ inline F3 f3cross(F3 a, F3 b) {
    return {a.y*b.z - a.z*b.y, a.z*b.x - a.x*b.z, a.x*b.y - a.y*b.x};
}
__device__ inline float f3dot(F3 a, F3 b) { return a.x*b.x + a.y*b.y + a.z*b.z; }

__device__ inline float dihedral(F3 p0, F3 p1, F3 p2, F3 p3) {
    F3 v0 = f3sub(p2, p1);
    F3 v1 = f3sub(p0, p1);
    F3 v2 = f3sub(p3, p2);
    F3 u1 = f3cross(v0, v1);
    F3 u2 = f3cross(v0, v2);
    float in1 = rsqrtf(f3dot(u1, u1) + 1e-10f);
    float in2 = rsqrtf(f3dot(u2, u2) + 1e-10f);
    F3 n1 = {u1.x*in1, u1.y*in1, u1.z*in1};
    F3 n2 = {u2.x*in2, u2.y*in2, u2.z*in2};
    F3 cr = f3cross(v0, n1);
    float s = f3dot(cr, n2);
    float sgn = (s > 0.f) ? 1.f : ((s < 0.f) ? -1.f : 0.f);
    float c = f3dot(n1, n2);
    c = fminf(fmaxf(c, -1.f + 1e-7f), 1.f - 1e-7f);
    return sgn * acosf(c);
}

// matvec over this wave's 8 pairs; lane owns columns c0 and c0+64.
// out[m][c] = act( sum_k in[m][k] * W[k*128+c] + b[c] )
template<int K, bool RELU>
__device__ inline void matvec(const float* s_in, int ldin, int m0,
                              const float* __restrict__ W,
                              const float* __restrict__ b,
                              int c0, float* s_out, int ldout)
{
    float acc0[8], acc1[8];
#pragma unroll
    for (int mm = 0; mm < 8; ++mm) { acc0[mm] = 0.f; acc1[mm] = 0.f; }
    constexpr int K4 = K & ~3;
    for (int k = 0; k < K4; k += 4) {
        float w00 = W[(k+0)*FEAT_DIM + c0], w01 = W[(k+0)*FEAT_DIM + c0 + 64];
        float w10 = W[(k+1)*FEAT_DIM + c0], w11 = W[(k+1)*FEAT_DIM + c0 + 64];
        float w20 = W[(k+2)*FEAT_DIM + c0], w21 = W[(k+2)*FEAT_DIM + c0 + 64];
        float w30 = W[(k+3)*FEAT_DIM + c0], w31 = W[(k+3)*FEAT_DIM + c0 + 64];
#pragma unroll
        for (int mm = 0; mm < 8; ++mm) {
            const float4 f = *(const float4*)(s_in + (m0+mm)*ldin + k);
            acc0[mm] = fmaf(f.w, w30, fmaf(f.z, w20, fmaf(f.y, w10, fmaf(f.x, w00, acc0[mm]))));
            acc1[mm] = fmaf(f.w, w31, fmaf(f.z, w21, fmaf(f.y, w11, fmaf(f.x, w01, acc1[mm]))));
        }
    }
    for (int k = K4; k < K; ++k) {
        float wa = W[k*FEAT_DIM + c0], wb = W[k*FEAT_DIM + c0 + 64];
#pragma unroll
        for (int mm = 0; mm < 8; ++mm) {
            float f = s_in[(m0+mm)*ldin + k];
            acc0[mm] = fmaf(f, wa, acc0[mm]);
            acc1[mm] = fmaf(f, wb, acc1[mm]);
        }
    }
    float b0 = b[c0], b1 = b[c0 + 64];
#pragma unroll
    for (int mm = 0; mm < 8; ++mm) {
        float r0 = acc0[mm] + b0, r1 = acc1[mm] + b1;
        if (RELU) { r0 = fmaxf(r0, 0.f); r1 = fmaxf(r1, 0.f); }
        s_out[(m0+mm)*ldout + c0]      = r0;
        s_out[(m0+mm)*ldout + c0 + 64] = r1;
    }
}

// last layer: no relu, multiply by mask_pair, write to global
__device__ inline void matvec_out(const float* s_in, int ldin, int m0,
                                  const float* __restrict__ W,
                                  const float* __restrict__ b,
                                  int c0, const float* s_mpair,
                                  float* __restrict__ out, int ri, int j0)
{
    float acc0[8], acc1[8];
#pragma unroll
    for (int mm = 0; mm < 8; ++mm) { acc0[mm] = 0.f; acc1[mm] = 0.f; }
    for (int k = 0; k < FEAT_DIM; k += 4) {
        float w00 = W[(k+0)*FEAT_DIM + c0], w01 = W[(k+0)*FEAT_DIM + c0 + 64];
        float w10 = W[(k+1)*FEAT_DIM + c0], w11 = W[(k+1)*FEAT_DIM + c0 + 64];
        float w20 = W[(k+2)*FEAT_DIM + c0], w21 = W[(k+2)*FEAT_DIM + c0 + 64];
        float w30 = W[(k+3)*FEAT_DIM + c0], w31 = W[(k+3)*FEAT_DIM + c0 + 64];
#pragma unroll
        for (int mm = 0; mm < 8; ++mm) {
            const float4 f = *(const float4*)(s_in + (m0+mm)*ldin + k);
            acc0[mm] = fmaf(f.w, w30, fmaf(f.z, w20, fmaf(f.y, w10, fmaf(f.x, w00, acc0[mm]))));
            acc1[mm] = fmaf(f.w, w31, fmaf(f.z, w21, fmaf(f.y, w11, fmaf(f.x, w01, acc1[mm]))));
        }
    }
    float b0 = b[c0], b1 = b[c0 + 64];
#pragma unroll
    for (int mm = 0; mm < 8; ++mm) {
        int j = j0 + m0 + mm;
        float mp = s_mpair[m0 + mm];
        float* o = out + ((size_t)(ri * L_SEQ + j)) * FEAT_DIM;
        o[c0]      = (acc0[mm] + b0) * mp;
        o[c0 + 64] = (acc1[mm] + b1) * mp;
    }
}

__global__ __launch_bounds__(128)
void rpe_kernel(const int* __restrict__ aa, const int* __restrict__ res_nb,
                const int* __restrict__ chain_nb,
                const float* __restrict__ pos_atoms, const float* __restrict__ mask_atoms,
                const float* __restrict__ aa_embed_w, const float* __restrict__ relpos_embed_w,
                const float* __restrict__ distcoef_w,
                const float* __restrict__ dist_w1, const float* __restrict__ dist_b1,
                const float* __restrict__ dist_w2, const float* __restrict__ dist_b2,
                const float* __restrict__ out_w1, const float* __restrict__ out_b1,
                const float* __restrict__ out_w2, const float* __restrict__ out_b2,
                const float* __restrict__ out_w3, const float* __restrict__ out_b3,
                float* __restrict__ out)
{
    const int tid = threadIdx.x;
    const int bid = blockIdx.x;           // 0..8191
    const int n  = bid >> 12;             // 4096 tiles per batch element
    const int i  = (bid >> 4) & 255;
    const int j0 = (bid & 15) << 4;
    const int ri = n * L_SEQ + i;

    __shared__ float s_feat[TM][416];     // 0:128 aapair | 128:256 relpos | 256:384 dist | 384:410 dihed
    __shared__ float s_g[TM][228];        // gauss vector (225) / later reused as h2
    __shared__ float s_h1[TM][128];
    __shared__ float s_posi[MAX_ATOMS][3];
    __shared__ float s_maski[MAX_ATOMS];
    __shared__ float s_posj[TM][MAX_ATOMS][3];
    __shared__ float s_maskj[TM][MAX_ATOMS];
    __shared__ int   s_aap[TM];
    __shared__ int   s_rp[TM];
    __shared__ float s_same[TM];
    __shared__ float s_mpair[TM];

    // ---- stage residue data ----
    if (tid < MAX_ATOMS * 3) ((float*)s_posi)[tid] = pos_atoms[ri * MAX_ATOMS * 3 + tid];
    if (tid >= 64 && tid < 64 + MAX_ATOMS) s_maski[tid - 64] = mask_atoms[ri * MAX_ATOMS + tid - 64];
    for (int idx = tid; idx < TM * MAX_ATOMS * 3; idx += 128)
        ((float*)s_posj)[idx] = pos_atoms[(n * L_SEQ + j0) * MAX_ATOMS * 3 + idx];
    for (int idx = tid; idx < TM * MAX_ATOMS; idx += 128)
        ((float*)s_maskj)[idx] = mask_atoms[(n * L_SEQ + j0) * MAX_ATOMS + idx];
    if (tid < TM) {
        int rj = n * L_SEQ + j0 + tid;
        int aai = aa[ri], aaj = aa[rj];
        s_aap[tid] = aai * MAX_AA + aaj;
        int d = res_nb[ri] - res_nb[rj];
        d = min(max(d, -MAX_RELPOS), MAX_RELPOS);
        s_rp[tid] = d + MAX_RELPOS;
        s_same[tid] = (chain_nb[ri] == chain_nb[rj]) ? 1.0f : 0.0f;
    }
    __syncthreads();

    if (tid < TM) s_mpair[tid] = s_maski[1] * s_maskj[tid][1];  // BB_CA = 1

    // ---- gaussian distance features ----
    for (int m = 0; m < TM; ++m) {
        const int ap = s_aap[m];
        for (int k = tid; k < KG; k += 128) {
            int a = k / MAX_ATOMS, b = k % MAX_ATOMS;
            float dx = s_posi[a][0] - s_posj[m][b][0];
            float dy = s_posi[a][1] - s_posj[m][b][1];
            float dz = s_posi[a][2] - s_posj[m][b][2];
            float d = sqrtf(dx*dx + dy*dy + dz*dz + 1e-10f) * 0.1f;
            float cw = distcoef_w[ap * KG + k];
            float c = (cw > 20.0f) ? cw : log1pf(expf(cw));      // softplus
            float g = expf(-c * d * d) * s_maski[a] * s_maskj[m][b];
            s_g[m][k] = g;
        }
    }

    // ---- aa-pair + relpos embedding gathers ----
    for (int m = 0; m < TM; ++m) {
        s_feat[m][tid]       = aa_embed_w[s_aap[m] * FEAT_DIM + tid];
        s_feat[m][128 + tid] = s_same[m] * relpos_embed_w[s_rp[m] * FEAT_DIM + tid];
    }

    // ---- dihedral features (threads 0..31: one (pair, angle) each) ----
    if (tid < 2 * TM) {
        int m = tid >> 1, which = tid & 1;
        F3 P0, P1, P2, P3;
        if (which == 0) {  // phi: pC_i, pN_j, pCA_j, pC_j
            P0 = {s_posi[2][0], s_posi[2][1], s_posi[2][2]};
            P1 = {s_posj[m][0][0], s_posj[m][0][1], s_posj[m][0][2]};
            P2 = {s_posj[m][1][0], s_posj[m][1][1], s_posj[m][1][2]};
            P3 = {s_posj[m][2][0], s_posj[m][2][1], s_posj[m][2][2]};
        } else {           // psi: pN_i, pCA_i, pC_i, pN_j
            P0 = {s_posi[0][0], s_posi[0][1], s_posi[0][2]};
            P1 = {s_posi[1][0], s_posi[1][1], s_posi[1][2]};
            P2 = {s_posi[2][0], s_posi[2][1], s_posi[2][2]};
            P3 = {s_posj[m][0][0], s_posj[m][0][1], s_posj[m][0][2]};
        }
        float x = dihedral(P0, P1, P2, P3);
        float* o = &s_feat[m][3 * FEAT_DIM + which * 13];
        o[0]  = x;
        o[1]  = sinf(x);        o[2]  = sinf(2.f*x); o[3] = sinf(3.f*x);
        o[4]  = sinf(x);        o[5]  = sinf(0.5f*x); o[6] = sinf(x * (1.f/3.f));
        o[7]  = cosf(x);        o[8]  = cosf(2.f*x); o[9] = cosf(3.f*x);
        o[10] = cosf(x);        o[11] = cosf(0.5f*x); o[12] = cosf(x * (1.f/3.f));
    }
    __syncthreads();

    const int wv = tid >> 6, lane = tid & 63;
    const int m0 = wv * 8, c0 = lane;

    // dist MLP
    matvec<KG, true>(&s_g[0][0], 228, m0, dist_w1, dist_b1, c0, &s_h1[0][0], 128);
    __syncthreads();
    matvec<128, true>(&s_h1[0][0], 128, m0, dist_w2, dist_b2, c0, &s_feat[0][256], 416);
    __syncthreads();
    // out MLP
    matvec<KF, true>(&s_feat[0][0], 416, m0, out_w1, out_b1, c0, &s_h1[0][0], 128);
    __syncthreads();
    matvec<128, true>(&s_h1[0][0], 128, m0, out_w2, out_b2, c0, &s_g[0][0], 228);
    __syncthreads();
    matvec_out(&s_g[0][0], 228, m0, out_w3, out_b3, c0, s_mpair, out, ri, j0);
}

extern "C" void kernel_launch(void* const* d_in, const int* in_sizes, int n_in,
                              void* d_out, int out_size, void* d_ws, size_t ws_size,
                              hipStream_t stream) {
    const int*   aa            = (const int*)  d_in[0];
    const int*   res_nb        = (const int*)  d_in[1];
    const int*   chain_nb      = (const int*)  d_in[2];
    const float* pos_atoms     = (const float*)d_in[3];
    const float* mask_atoms    = (const float*)d_in[4];
    const float* aa_embed_w    = (const float*)d_in[5];
    const float* relpos_embed_w= (const float*)d_in[6];
    const float* distcoef_w    = (const float*)d_in[7];
    const float* dist_w1       = (const float*)d_in[8];
    const float* dist_b1       = (const float*)d_in[9];
    const float* dist_w2       = (const float*)d_in[10];
    const float* dist_b2       = (const float*)d_in[11];
    const float* out_w1        = (const float*)d_in[12];
    const float* out_b1        = (const float*)d_in[13];
    const float* out_w2        = (const float*)d_in[14];
    const float* out_b2        = (const float*)d_in[15];
    const float* out_w3        = (const float*)d_in[16];
    const float* out_b3        = (const float*)d_in[17];
    float* out = (float*)d_out;

    const int nblocks = 2 * L_SEQ * (L_SEQ / TM);  // 8192
    hipLaunchKernelGGL(rpe_kernel, dim3(nblocks), dim3(128), 0, stream,
                       aa, res_nb, chain_nb, pos_atoms, mask_atoms,
                       aa_embed_w, relpos_embed_w, distcoef_w,
                       dist_w1, dist_b1, dist_w2, dist_b2,
                       out_w1, out_b1, out_w2, out_b2, out_w3, out_b3, out);
}

// Round 4
// 508.304 us; speedup vs baseline: 2.1767x; 2.1767x over previous
//
#include <hip/hip_runtime.h>
#include <math.h>

typedef __attribute__((ext_vector_type(8))) short bf16x8;
typedef __attribute__((ext_vector_type(4))) float f32x4;
typedef unsigned short u16;

#define L_SEQ 256
#define TM2 16
#define MFMA __builtin_amdgcn_mfma_f32_16x16x32_bf16

// ws element offsets (u16 elements), layout identical to R3.
#define WS_B1   0        // dist_w1: Kp=256 (K=225), 8 kt
#define WS_B2   32768    // dist_w2: Kp=128, 4 kt
#define WS_B3   49152
#define WS_B4   102400
#define WS_B5   118784
#define WS_L4LO 135168
#define WS_L5LO 151552
#define WS_TOTAL 167936

__device__ inline u16 f2bf(float f){
    unsigned u = __float_as_uint(f);
    unsigned r = (u + 0x7FFFu + ((u >> 16) & 1u)) >> 16;
    return (u16)r;
}
__device__ inline float bf2f(u16 h){ return __uint_as_float(((unsigned)h) << 16); }
__device__ inline int swz(int m, int k, int lda){ return m*lda + (k ^ ((m & 7) << 3)); }

struct F3 { float x, y, z; };
__device__ inline F3 f3sub(F3 a, F3 b){ return {a.x-b.x, a.y-b.y, a.z-b.z}; }
__device__ inline F3 f3cross(F3 a, F3 b){
    return {a.y*b.z - a.z*b.y, a.z*b.x - a.x*b.z, a.x*b.y - a.y*b.x};
}
__device__ inline float f3dot(F3 a, F3 b){ return a.x*b.x + a.y*b.y + a.z*b.z; }

__device__ inline float dihedral(F3 p0, F3 p1, F3 p2, F3 p3){
    F3 v0 = f3sub(p2, p1);
    F3 v1 = f3sub(p0, p1);
    F3 v2 = f3sub(p3, p2);
    F3 u1 = f3cross(v0, v1);
    F3 u2 = f3cross(v0, v2);
    float in1 = rsqrtf(f3dot(u1, u1) + 1e-10f);
    float in2 = rsqrtf(f3dot(u2, u2) + 1e-10f);
    F3 n1 = {u1.x*in1, u1.y*in1, u1.z*in1};
    F3 n2 = {u2.x*in2, u2.y*in2, u2.z*in2};
    float s = f3dot(f3cross(v0, n1), n2);
    float sgn = (s > 0.f) ? 1.f : ((s < 0.f) ? -1.f : 0.f);
    float c = f3dot(n1, n2);
    c = fminf(fmaxf(c, -1.f + 1e-7f), 1.f - 1e-7f);
    return sgn * acosf(c);
}

// ---------------- weight split+pack prep kernel (unchanged) ----------------
__global__ __launch_bounds__(256)
void prep_w(const float* __restrict__ w1, const float* __restrict__ w2,
            const float* __restrict__ w3, const float* __restrict__ w4,
            const float* __restrict__ w5, u16* __restrict__ ws)
{
    int idx = blockIdx.x * 256 + threadIdx.x;
    if (idx >= WS_TOTAL) return;
    const float* W; int Kreal, rel; bool lo = false;
    if      (idx < WS_B2)   { W = w1; Kreal = 225; rel = idx; }
    else if (idx < WS_B3)   { W = w2; Kreal = 128; rel = idx - WS_B2; }
    else if (idx < WS_B4)   { W = w3; Kreal = 410; rel = idx - WS_B3; }
    else if (idx < WS_B5)   { W = w4; Kreal = 128; rel = idx - WS_B4; }
    else if (idx < WS_L4LO) { W = w5; Kreal = 128; rel = idx - WS_B5; }
    else if (idx < WS_L5LO) { W = w4; Kreal = 128; rel = idx - WS_L4LO; lo = true; }
    else                    { W = w5; Kreal = 128; rel = idx - WS_L5LO; lo = true; }
    int e = rel & 7, lane = (rel >> 3) & 63, ct = (rel >> 9) & 7, kt = rel >> 12;
    int k = kt*32 + ((lane >> 4) << 3) + e;
    int col = ct*16 + (lane & 15);
    float v = (k < Kreal) ? W[k*128 + col] : 0.f;
    u16 h = f2bf(v);
    ws[idx] = lo ? f2bf(v - bf2f(h)) : h;
}

// ---------------- 16-row MFMA gemm (single m-tile) ----------------
template<int T>
__device__ inline void gemm16(const u16* __restrict__ A, int lda,
                              const u16* __restrict__ B,
                              int ct0, int lane, f32x4 acc[2])
{
    const int r15 = lane & 15;
    const int koff = (lane >> 4) << 3;
    const int sx = (r15 & 7) << 3;
    const u16* ap = A + r15*lda;
#pragma unroll
    for (int kt = 0; kt < T; ++kt){
        int kk = ((kt << 5) + koff) ^ sx;
        bf16x8 a = *(const bf16x8*)(ap + kk);
        const u16* bp = B + (((kt*8 + ct0)*64 + lane) << 3);
        bf16x8 b0 = *(const bf16x8*)(bp);
        bf16x8 b1 = *(const bf16x8*)(bp + 512);
        acc[0] = MFMA(a, b0, acc[0], 0, 0, 0);
        acc[1] = MFMA(a, b1, acc[1], 0, 0, 0);
    }
}

// ---------------- f32 matvec, 4 pairs per wave (R1-proven structure) ----------------
template<int K, bool RELU>
__device__ inline void matvec4(const float* s_in, int ldin, int m0,
                               const float* __restrict__ W,
                               const float* __restrict__ b,
                               int c0, float* s_out, int ldout)
{
    float acc0[4], acc1[4];
#pragma unroll
    for (int mm = 0; mm < 4; ++mm) { acc0[mm] = 0.f; acc1[mm] = 0.f; }
    constexpr int K4 = K & ~3;
    for (int k = 0; k < K4; k += 4) {
        float w00 = W[(k+0)*128 + c0], w01 = W[(k+0)*128 + c0 + 64];
        float w10 = W[(k+1)*128 + c0], w11 = W[(k+1)*128 + c0 + 64];
        float w20 = W[(k+2)*128 + c0], w21 = W[(k+2)*128 + c0 + 64];
        float w30 = W[(k+3)*128 + c0], w31 = W[(k+3)*128 + c0 + 64];
#pragma unroll
        for (int mm = 0; mm < 4; ++mm) {
            const float4 f = *(const float4*)(s_in + (m0+mm)*ldin + k);
            acc0[mm] = fmaf(f.w, w30, fmaf(f.z, w20, fmaf(f.y, w10, fmaf(f.x, w00, acc0[mm]))));
            acc1[mm] = fmaf(f.w, w31, fmaf(f.z, w21, fmaf(f.y, w11, fmaf(f.x, w01, acc1[mm]))));
        }
    }
    for (int k = K4; k < K; ++k) {
        float wa = W[k*128 + c0], wb = W[k*128 + c0 + 64];
#pragma unroll
        for (int mm = 0; mm < 4; ++mm) {
            float f = s_in[(m0+mm)*ldin + k];
            acc0[mm] = fmaf(f, wa, acc0[mm]);
            acc1[mm] = fmaf(f, wb, acc1[mm]);
        }
    }
    float b0 = b[c0], b1 = b[c0 + 64];
#pragma unroll
    for (int mm = 0; mm < 4; ++mm) {
        float r0 = acc0[mm] + b0, r1 = acc1[mm] + b1;
        if (RELU) { r0 = fmaxf(r0, 0.f); r1 = fmaxf(r1, 0.f); }
        s_out[(m0+mm)*ldout + c0]      = r0;
        s_out[(m0+mm)*ldout + c0 + 64] = r1;
    }
}

// ---------------- main diagnostic kernel ----------------
__global__ __launch_bounds__(256, 2)
void rpe_diag(const int* __restrict__ aa, const int* __restrict__ res_nb,
              const int* __restrict__ chain_nb,
              const float* __restrict__ pos_atoms, const float* __restrict__ mask_atoms,
              const float* __restrict__ aa_embed_w, const float* __restrict__ relpos_embed_w,
              const float* __restrict__ distcoef_w,
              const float* __restrict__ dist_b1, const float* __restrict__ dist_b2,
              const float* __restrict__ out_w1f, const float* __restrict__ out_b1,
              const float* __restrict__ out_w2f, const float* __restrict__ out_b2,
              const float* __restrict__ out_w3f, const float* __restrict__ out_b3,
              const u16* __restrict__ ws, float* __restrict__ out)
{
    const int t = threadIdx.x;
    const int bid = blockIdx.x;
    const int n  = bid >> 12;
    const int i  = (bid >> 4) & 255;
    const int j0 = (bid & 15) << 4;
    const int ri = n*L_SEQ + i;
    const int rj0 = n*L_SEQ + j0;

    __shared__ __align__(16) u16   s_g[TM2*256];    // gauss bf16 swizzled
    __shared__ __align__(16) u16   s_hh[TM2*128];   // h1 bf16 swizzled
    __shared__ __align__(16) float s_F[TM2][424];   // f32 features: aap|relpos|dist|dihed ; later h4 in [0:128)
    __shared__ __align__(16) float s_H[TM2][128];   // h3 f32
    __shared__ __align__(16) float s_stage[1024];   // dedicated staging (never reused)
    __shared__ int   s_aap[TM2];
    __shared__ int   s_rp[TM2];
    __shared__ float s_same[TM2];

    float* u_posj  = s_stage;          // [16*45)
    float* u_posi  = s_stage + 720;    // 45
    float* u_maskj = s_stage + 768;    // 240
    float* u_maski = s_stage + 1008;   // 15

    // ---- stage residue data ----
    for (int idx = t; idx < TM2*45; idx += 256) u_posj[idx] = pos_atoms[rj0*45 + idx];
    if (t < 45) u_posi[t] = pos_atoms[ri*45 + t];
    for (int idx = t; idx < TM2*15; idx += 256) u_maskj[idx] = mask_atoms[rj0*15 + idx];
    if (t >= 64 && t < 79) u_maski[t - 64] = mask_atoms[ri*15 + (t - 64)];
    if (t >= 96 && t < 96 + TM2){
        int m = t - 96, rj = rj0 + m;
        s_aap[m] = aa[ri]*22 + aa[rj];
        int d = res_nb[ri] - res_nb[rj];
        d = min(max(d, -32), 32);
        s_rp[m] = d + 32;
        s_same[m] = (chain_nb[ri] == chain_nb[rj]) ? 1.f : 0.f;
    }
    __syncthreads();

    // ---- gaussian distance features (bf16 hi, swizzled) ----
    for (int idx = t; idx < TM2*225; idx += 256){
        int m = idx / 225, k = idx - m*225;
        int a = k / 15, b = k - a*15;
        float dx = u_posi[a*3+0] - u_posj[m*45 + b*3+0];
        float dy = u_posi[a*3+1] - u_posj[m*45 + b*3+1];
        float dz = u_posi[a*3+2] - u_posj[m*45 + b*3+2];
        float d2 = (dx*dx + dy*dy + dz*dz + 1e-10f) * 0.01f;
        float cw = distcoef_w[s_aap[m]*225 + k];
        float c = fmaxf(cw, 0.f) + log1pf(expf(-fabsf(cw)));
        float g = expf(-c*d2) * u_maski[a] * u_maskj[m*15 + b];
        s_g[swz(m, k, 256)] = f2bf(g);
    }
    for (int idx = t; idx < TM2*31; idx += 256){ int m = idx/31; s_g[swz(m, 225 + idx - m*31, 256)] = 0; }

    // ---- embedding gathers (f32 into s_F) ----
    for (int idx = t; idx < TM2*128; idx += 256){
        int m = idx >> 7, c = idx & 127;
        s_F[m][c]       = aa_embed_w[s_aap[m]*128 + c];
        s_F[m][128 + c] = s_same[m] * relpos_embed_w[s_rp[m]*128 + c];
    }

    // ---- dihedral features (f32 into s_F cols 384..409) ----
    if (t < 2*TM2){
        int m = t >> 1, w = t & 1;
        F3 P0, P1, P2, P3;
        if (w == 0){   // phi: pC_i, pN_j, pCA_j, pC_j
            P0 = {u_posi[6],  u_posi[7],  u_posi[8]};
            P1 = {u_posj[m*45+0], u_posj[m*45+1], u_posj[m*45+2]};
            P2 = {u_posj[m*45+3], u_posj[m*45+4], u_posj[m*45+5]};
            P3 = {u_posj[m*45+6], u_posj[m*45+7], u_posj[m*45+8]};
        } else {       // psi: pN_i, pCA_i, pC_i, pN_j
            P0 = {u_posi[0], u_posi[1], u_posi[2]};
            P1 = {u_posi[3], u_posi[4], u_posi[5]};
            P2 = {u_posi[6], u_posi[7], u_posi[8]};
            P3 = {u_posj[m*45+0], u_posj[m*45+1], u_posj[m*45+2]};
        }
        float x = dihedral(P0, P1, P2, P3);
        float* o = &s_F[m][384 + w*13];
        o[0]  = x;
        o[1]  = sinf(x);       o[2]  = sinf(2.f*x);  o[3]  = sinf(3.f*x);
        o[4]  = sinf(x);       o[5]  = sinf(0.5f*x); o[6]  = sinf(x*(1.f/3.f));
        o[7]  = cosf(x);       o[8]  = cosf(2.f*x);  o[9]  = cosf(3.f*x);
        o[10] = cosf(x);       o[11] = cosf(0.5f*x); o[12] = cosf(x*(1.f/3.f));
    }
    __syncthreads();

    const int lane = t & 63;
    const int wv = t >> 6;
    const int ct0 = wv * 2;

    // ---- L1: h1 = relu(g @ W1 + b1)  [MFMA] ----
    f32x4 acc[2];
    acc[0] = {0,0,0,0}; acc[1] = {0,0,0,0};
    gemm16<8>(s_g, 256, ws + WS_B1, ct0, lane, acc);
    {
        const int rr = (lane >> 4) << 2;
#pragma unroll
        for (int ct = 0; ct < 2; ++ct){
            int col = (ct0 + ct)*16 + (lane & 15);
            float b = dist_b1[col];
#pragma unroll
            for (int r = 0; r < 4; ++r){
                int m = rr + r;
                float v = fmaxf(acc[ct][r] + b, 0.f);
                s_hh[m*128 + (col ^ ((m & 7) << 3))] = f2bf(v);
            }
        }
    }
    __syncthreads();

    // ---- L2: feat_dist = relu(h1 @ W2 + b2)  [MFMA] -> f32 straight into s_F ----
    acc[0] = {0,0,0,0}; acc[1] = {0,0,0,0};
    gemm16<4>(s_hh, 128, ws + WS_B2, ct0, lane, acc);
    {
        const int rr = (lane >> 4) << 2;
#pragma unroll
        for (int ct = 0; ct < 2; ++ct){
            int col = (ct0 + ct)*16 + (lane & 15);
            float b = dist_b2[col];
#pragma unroll
            for (int r = 0; r < 4; ++r){
                int m = rr + r;
                s_F[m][256 + col] = fmaxf(acc[ct][r] + b, 0.f);
            }
        }
    }
    __syncthreads();

    // ---- L3..L5: proven f32 matvec path ----
    matvec4<410, true>(&s_F[0][0], 424, wv*4, out_w1f, out_b1, lane, &s_H[0][0], 128);
    __syncthreads();
    matvec4<128, true>(&s_H[0][0], 128, wv*4, out_w2f, out_b2, lane, &s_F[0][0], 424);
    __syncthreads();
    // L5 -> global, with mask_pair
    {
        const int m0 = wv*4, c0 = lane;
        float acc0[4], acc1[4];
#pragma unroll
        for (int mm = 0; mm < 4; ++mm){ acc0[mm] = 0.f; acc1[mm] = 0.f; }
        for (int k = 0; k < 128; k += 4){
            float w00 = out_w3f[(k+0)*128 + c0], w01 = out_w3f[(k+0)*128 + c0 + 64];
            float w10 = out_w3f[(k+1)*128 + c0], w11 = out_w3f[(k+1)*128 + c0 + 64];
            float w20 = out_w3f[(k+2)*128 + c0], w21 = out_w3f[(k+2)*128 + c0 + 64];
            float w30 = out_w3f[(k+3)*128 + c0], w31 = out_w3f[(k+3)*128 + c0 + 64];
#pragma unroll
            for (int mm = 0; mm < 4; ++mm){
                const float4 f = *(const float4*)(&s_F[m0+mm][k]);
                acc0[mm] = fmaf(f.w, w30, fmaf(f.z, w20, fmaf(f.y, w10, fmaf(f.x, w00, acc0[mm]))));
                acc1[mm] = fmaf(f.w, w31, fmaf(f.z, w21, fmaf(f.y, w11, fmaf(f.x, w01, acc1[mm]))));
            }
        }
        float b0 = out_b3[c0], b1 = out_b3[c0 + 64];
        float mi = mask_atoms[ri*15 + 1];
#pragma unroll
        for (int mm = 0; mm < 4; ++mm){
            int m = m0 + mm;
            float mp = mi * mask_atoms[(rj0 + m)*15 + 1];
            float* o = out + ((size_t)(ri*L_SEQ) + (size_t)(j0 + m))*128;
            o[c0]      = (acc0[mm] + b0) * mp;
            o[c0 + 64] = (acc1[mm] + b1) * mp;
        }
    }
}

extern "C" void kernel_launch(void* const* d_in, const int* in_sizes, int n_in,
                              void* d_out, int out_size, void* d_ws, size_t ws_size,
                              hipStream_t stream) {
    const int*   aa             = (const int*)  d_in[0];
    const int*   res_nb         = (const int*)  d_in[1];
    const int*   chain_nb       = (const int*)  d_in[2];
    const float* pos_atoms      = (const float*)d_in[3];
    const float* mask_atoms     = (const float*)d_in[4];
    const float* aa_embed_w     = (const float*)d_in[5];
    const float* relpos_embed_w = (const float*)d_in[6];
    const float* distcoef_w     = (const float*)d_in[7];
    const float* dist_w1        = (const float*)d_in[8];
    const float* dist_b1        = (const float*)d_in[9];
    const float* dist_w2        = (const float*)d_in[10];
    const float* dist_b2        = (const float*)d_in[11];
    const float* out_w1         = (const float*)d_in[12];
    const float* out_b1         = (const float*)d_in[13];
    const float* out_w2         = (const float*)d_in[14];
    const float* out_b2         = (const float*)d_in[15];
    const float* out_w3         = (const float*)d_in[16];
    const float* out_b3         = (const float*)d_in[17];
    float* out = (float*)d_out;
    u16* ws = (u16*)d_ws;

    hipLaunchKernelGGL(prep_w, dim3((WS_TOTAL + 255)/256), dim3(256), 0, stream,
                       dist_w1, dist_w2, out_w1, out_w2, out_w3, ws);

    const int nblocks = 2 * L_SEQ * (L_SEQ / TM2);   // 8192
    hipLaunchKernelGGL(rpe_diag, dim3(nblocks), dim3(256), 0, stream,
                       aa, res_nb, chain_nb, pos_atoms, mask_atoms,
                       aa_embed_w, relpos_embed_w, distcoef_w,
                       dist_b1, dist_b2, out_w1, out_b1, out_w2, out_b2, out_w3, out_b3,
                       ws, out);
}

// Round 5
// 227.550 us; speedup vs baseline: 4.8624x; 2.2338x over previous
//
#include <hip/hip_runtime.h>
#include <math.h>

typedef __attribute__((ext_vector_type(8))) short bf16x8;
typedef __attribute__((ext_vector_type(4))) float f32x4;
typedef unsigned short u16;

#define L_SEQ 256
#define TMP 16
#define MFMA __builtin_amdgcn_mfma_f32_16x16x32_bf16

// ws element offsets (u16 elements). Packed B-fragment layout per layer:
// [kt][ct(8)][lane(64)][e(8)], elem = W[kt*32 + (lane>>4)*8 + e][ct*16 + (lane&15)]
#define WS_B1   0        // dist_w1: Kp=256 (K=225), 8 kt
#define WS_B2   32768    // dist_w2: Kp=128, 4 kt
#define WS_B3   49152    // out_w1:  Kp=416 (K=410), 13 kt
#define WS_B4   102400   // out_w2:  Kp=128
#define WS_B5   118784   // out_w3:  Kp=128
#define WS_L4LO 135168   // lo parts, out_w2
#define WS_L5LO 151552   // lo parts, out_w3
#define WS_TOTAL 167936

__device__ inline u16 f2bf(float f){
    unsigned u = __float_as_uint(f);
    unsigned r = (u + 0x7FFFu + ((u >> 16) & 1u)) >> 16;
    return (u16)r;
}
__device__ inline float bf2f(u16 h){ return __uint_as_float(((unsigned)h) << 16); }
__device__ inline int swz(int m, int k, int lda){ return m*lda + (k ^ ((m & 7) << 3)); }

struct F3 { float x, y, z; };
__device__ inline F3 f3sub(F3 a, F3 b){ return {a.x-b.x, a.y-b.y, a.z-b.z}; }
__device__ inline F3 f3cross(F3 a, F3 b){
    return {a.y*b.z - a.z*b.y, a.z*b.x - a.x*b.z, a.x*b.y - a.y*b.x};
}
__device__ inline float f3dot(F3 a, F3 b){ return a.x*b.x + a.y*b.y + a.z*b.z; }

__device__ inline float dihedral(F3 p0, F3 p1, F3 p2, F3 p3){
    F3 v0 = f3sub(p2, p1);
    F3 v1 = f3sub(p0, p1);
    F3 v2 = f3sub(p3, p2);
    F3 u1 = f3cross(v0, v1);
    F3 u2 = f3cross(v0, v2);
    float in1 = rsqrtf(f3dot(u1, u1) + 1e-10f);
    float in2 = rsqrtf(f3dot(u2, u2) + 1e-10f);
    F3 n1 = {u1.x*in1, u1.y*in1, u1.z*in1};
    F3 n2 = {u2.x*in2, u2.y*in2, u2.z*in2};
    float s = f3dot(f3cross(v0, n1), n2);
    float sgn = (s > 0.f) ? 1.f : ((s < 0.f) ? -1.f : 0.f);
    float c = f3dot(n1, n2);
    c = fminf(fmaxf(c, -1.f + 1e-7f), 1.f - 1e-7f);
    return sgn * acosf(c);
}

// ---------------- weight split+pack prep kernel (R4-proven layout) ----------------
__global__ __launch_bounds__(256)
void prep_w(const float* __restrict__ w1, const float* __restrict__ w2,
            const float* __restrict__ w3, const float* __restrict__ w4,
            const float* __restrict__ w5, u16* __restrict__ ws)
{
    int idx = blockIdx.x * 256 + threadIdx.x;
    if (idx >= WS_TOTAL) return;
    const float* W; int Kreal, rel; bool lo = false;
    if      (idx < WS_B2)   { W = w1; Kreal = 225; rel = idx; }
    else if (idx < WS_B3)   { W = w2; Kreal = 128; rel = idx - WS_B2; }
    else if (idx < WS_B4)   { W = w3; Kreal = 410; rel = idx - WS_B3; }
    else if (idx < WS_B5)   { W = w4; Kreal = 128; rel = idx - WS_B4; }
    else if (idx < WS_L4LO) { W = w5; Kreal = 128; rel = idx - WS_B5; }
    else if (idx < WS_L5LO) { W = w4; Kreal = 128; rel = idx - WS_L4LO; lo = true; }
    else                    { W = w5; Kreal = 128; rel = idx - WS_L5LO; lo = true; }
    int e = rel & 7, lane = (rel >> 3) & 63, ct = (rel >> 9) & 7, kt = rel >> 12;
    int k = kt*32 + ((lane >> 4) << 3) + e;
    int col = ct*16 + (lane & 15);
    float v = (k < Kreal) ? W[k*128 + col] : 0.f;
    u16 h = f2bf(v);
    ws[idx] = lo ? f2bf(v - bf2f(h)) : h;
}

// ---------------- single-m-tile MFMA gemm (R4-PROVEN) ----------------
template<int T>
__device__ inline void gemm16(const u16* __restrict__ A, int lda,
                              const u16* __restrict__ B,
                              int ct0, int lane, f32x4 acc[2])
{
    const int r15 = lane & 15;
    const int koff = (lane >> 4) << 3;
    const int sx = (r15 & 7) << 3;
    const u16* ap = A + r15*lda;
#pragma unroll
    for (int kt = 0; kt < T; ++kt){
        int kk = ((kt << 5) + koff) ^ sx;
        bf16x8 a = *(const bf16x8*)(ap + kk);
        const u16* bp = B + (((kt*8 + ct0)*64 + lane) << 3);
        bf16x8 b0 = *(const bf16x8*)(bp);
        bf16x8 b1 = *(const bf16x8*)(bp + 512);
        acc[0] = MFMA(a, b0, acc[0], 0, 0, 0);
        acc[1] = MFMA(a, b1, acc[1], 0, 0, 0);
    }
}

// split variant: acc += Ahi*Bhi + Ahi*Blo + Alo*Bhi  (same addressing as gemm16)
template<int T>
__device__ inline void gemm16s(const u16* __restrict__ Ah, const u16* __restrict__ Al, int lda,
                               const u16* __restrict__ Bh, const u16* __restrict__ Bl,
                               int ct0, int lane, f32x4 acc[2])
{
    const int r15 = lane & 15;
    const int koff = (lane >> 4) << 3;
    const int sx = (r15 & 7) << 3;
    const u16* ahp = Ah + r15*lda;
    const u16* alp = Al + r15*lda;
#pragma unroll
    for (int kt = 0; kt < T; ++kt){
        int kk = ((kt << 5) + koff) ^ sx;
        bf16x8 ah = *(const bf16x8*)(ahp + kk);
        bf16x8 al = *(const bf16x8*)(alp + kk);
        const int bo = ((kt*8 + ct0)*64 + lane) << 3;
#pragma unroll
        for (int ct = 0; ct < 2; ++ct){
            bf16x8 bh = *(const bf16x8*)(Bh + bo + ct*512);
            bf16x8 bl = *(const bf16x8*)(Bl + bo + ct*512);
            acc[ct] = MFMA(ah, bh, acc[ct], 0, 0, 0);
            acc[ct] = MFMA(ah, bl, acc[ct], 0, 0, 0);
            acc[ct] = MFMA(al, bh, acc[ct], 0, 0, 0);
        }
    }
}

// epilogue: bias+relu -> swizzled bf16 LDS (hi, optional lo). R4-proven mapping.
__device__ inline void epi16(f32x4 acc[2], const float* __restrict__ bias,
                             int ct0, int lane, u16* Dhi, u16* Dlo)
{
    const int rr = (lane >> 4) << 2;
#pragma unroll
    for (int ct = 0; ct < 2; ++ct){
        int col = (ct0 + ct)*16 + (lane & 15);
        float b = bias[col];
#pragma unroll
        for (int r = 0; r < 4; ++r){
            int m = rr + r;
            int idx = m*128 + (col ^ ((m & 7) << 3));
            float v = fmaxf(acc[ct][r] + b, 0.f);
            u16 h = f2bf(v);
            Dhi[idx] = h;
            if (Dlo) Dlo[idx] = f2bf(v - bf2f(h));
        }
    }
}

// ---------------- main fused kernel ----------------
__global__ __launch_bounds__(256, 2)
void rpe_mfma2(const int* __restrict__ aa, const int* __restrict__ res_nb,
               const int* __restrict__ chain_nb,
               const float* __restrict__ pos_atoms, const float* __restrict__ mask_atoms,
               const float* __restrict__ aa_embed_w, const float* __restrict__ relpos_embed_w,
               const float* __restrict__ distcoef_w,
               const float* __restrict__ dist_b1, const float* __restrict__ dist_b2,
               const float* __restrict__ out_b1, const float* __restrict__ out_b2,
               const float* __restrict__ out_b3,
               const u16* __restrict__ ws, float* __restrict__ out)
{
    const int t = threadIdx.x;
    const int bid = blockIdx.x;
    const int n  = bid >> 12;
    const int i  = (bid >> 4) & 255;
    const int j0 = (bid & 15) << 4;
    const int ri = n*L_SEQ + i;
    const int rj0 = n*L_SEQ + j0;

    __shared__ __align__(16) u16   s_g[TMP*256];    // gauss bf16, swz lda=256
    __shared__ __align__(16) u16   s_c1[TMP*256];   // aapair|relpos bf16, swz
    __shared__ __align__(16) u16   s_c2[TMP*128];   // dist feat bf16, swz
    __shared__ __align__(16) u16   s_c3[TMP*64];    // dihed bf16 (26+pad), swz
    __shared__ __align__(16) u16   s_h1[TMP*128];   // h1 bf16, swz
    __shared__ __align__(16) u16   s_h3h[TMP*128];  // h3 hi
    __shared__ __align__(16) u16   s_h3l[TMP*128];  // h3 lo
    __shared__ __align__(16) u16   s_h4h[TMP*128];  // h4 hi
    __shared__ __align__(16) u16   s_h4l[TMP*128];  // h4 lo
    __shared__ __align__(16) float s_stage[1024];   // dedicated staging, never reused
    __shared__ int   s_aap[TMP];
    __shared__ int   s_rp[TMP];
    __shared__ float s_same[TMP];

    float* u_posj  = s_stage;          // [16*45)
    float* u_posi  = s_stage + 720;    // 45
    float* u_maskj = s_stage + 768;    // 240
    float* u_maski = s_stage + 1008;   // 15

    // ---- stage residue data ----
    for (int idx = t; idx < TMP*45; idx += 256) u_posj[idx] = pos_atoms[rj0*45 + idx];
    if (t < 45) u_posi[t] = pos_atoms[ri*45 + t];
    for (int idx = t; idx < TMP*15; idx += 256) u_maskj[idx] = mask_atoms[rj0*15 + idx];
    if (t >= 64 && t < 79) u_maski[t - 64] = mask_atoms[ri*15 + (t - 64)];
    if (t >= 96 && t < 96 + TMP){
        int m = t - 96, rj = rj0 + m;
        s_aap[m] = aa[ri]*22 + aa[rj];
        int d = res_nb[ri] - res_nb[rj];
        d = min(max(d, -32), 32);
        s_rp[m] = d + 32;
        s_same[m] = (chain_nb[ri] == chain_nb[rj]) ? 1.f : 0.f;
    }
    __syncthreads();

    // ---- gaussian distance features (bf16 hi, swizzled) ----
    for (int idx = t; idx < TMP*225; idx += 256){
        int m = idx / 225, k = idx - m*225;
        int a = k / 15, b = k - a*15;
        float dx = u_posi[a*3+0] - u_posj[m*45 + b*3+0];
        float dy = u_posi[a*3+1] - u_posj[m*45 + b*3+1];
        float dz = u_posi[a*3+2] - u_posj[m*45 + b*3+2];
        float d2 = (dx*dx + dy*dy + dz*dz + 1e-10f) * 0.01f;
        float cw = distcoef_w[s_aap[m]*225 + k];
        float c = fmaxf(cw, 0.f) + log1pf(expf(-fabsf(cw)));
        float g = expf(-c*d2) * u_maski[a] * u_maskj[m*15 + b];
        s_g[swz(m, k, 256)] = f2bf(g);
    }
    for (int idx = t; idx < TMP*31; idx += 256){ int m = idx/31; s_g[swz(m, 225 + idx - m*31, 256)] = 0; }

    // ---- embedding gathers (bf16, swizzled) ----
    for (int idx = t; idx < TMP*128; idx += 256){
        int m = idx >> 7, c = idx & 127;
        s_c1[swz(m, c,       256)] = f2bf(aa_embed_w[s_aap[m]*128 + c]);
        s_c1[swz(m, 128 + c, 256)] = f2bf(s_same[m] * relpos_embed_w[s_rp[m]*128 + c]);
    }

    // ---- dihedral features (bf16 into s_c3) ----
    if (t < 2*TMP){
        int m = t >> 1, w = t & 1;
        F3 P0, P1, P2, P3;
        if (w == 0){   // phi: pC_i, pN_j, pCA_j, pC_j
            P0 = {u_posi[6],  u_posi[7],  u_posi[8]};
            P1 = {u_posj[m*45+0], u_posj[m*45+1], u_posj[m*45+2]};
            P2 = {u_posj[m*45+3], u_posj[m*45+4], u_posj[m*45+5]};
            P3 = {u_posj[m*45+6], u_posj[m*45+7], u_posj[m*45+8]};
        } else {       // psi: pN_i, pCA_i, pC_i, pN_j
            P0 = {u_posi[0], u_posi[1], u_posi[2]};
            P1 = {u_posi[3], u_posi[4], u_posi[5]};
            P2 = {u_posi[6], u_posi[7], u_posi[8]};
            P3 = {u_posj[m*45+0], u_posj[m*45+1], u_posj[m*45+2]};
        }
        float x = dihedral(P0, P1, P2, P3);
        int kb = w*13;
        s_c3[swz(m, kb+0,  64)] = f2bf(x);
        s_c3[swz(m, kb+1,  64)] = f2bf(sinf(x));
        s_c3[swz(m, kb+2,  64)] = f2bf(sinf(2.f*x));
        s_c3[swz(m, kb+3,  64)] = f2bf(sinf(3.f*x));
        s_c3[swz(m, kb+4,  64)] = f2bf(sinf(x));
        s_c3[swz(m, kb+5,  64)] = f2bf(sinf(0.5f*x));
        s_c3[swz(m, kb+6,  64)] = f2bf(sinf(x*(1.f/3.f)));
        s_c3[swz(m, kb+7,  64)] = f2bf(cosf(x));
        s_c3[swz(m, kb+8,  64)] = f2bf(cosf(2.f*x));
        s_c3[swz(m, kb+9,  64)] = f2bf(cosf(3.f*x));
        s_c3[swz(m, kb+10, 64)] = f2bf(cosf(x));
        s_c3[swz(m, kb+11, 64)] = f2bf(cosf(0.5f*x));
        s_c3[swz(m, kb+12, 64)] = f2bf(cosf(x*(1.f/3.f)));
    }
    for (int idx = t; idx < TMP*38; idx += 256){ int m = idx/38; s_c3[swz(m, 26 + idx - m*38, 64)] = 0; }
    __syncthreads();

    const int lane = t & 63;
    const int ct0 = (t >> 6) * 2;   // wave -> 2 col-tiles

    // ---- L1: h1 = relu(g @ W1 + b1) ----
    f32x4 acc[2];
    acc[0] = {0,0,0,0}; acc[1] = {0,0,0,0};
    gemm16<8>(s_g, 256, ws + WS_B1, ct0, lane, acc);
    epi16(acc, dist_b1, ct0, lane, s_h1, nullptr);
    __syncthreads();

    // ---- L2: feat_dist = relu(h1 @ W2 + b2) ----
    acc[0] = {0,0,0,0}; acc[1] = {0,0,0,0};
    gemm16<4>(s_h1, 128, ws + WS_B2, ct0, lane, acc);
    epi16(acc, dist_b2, ct0, lane, s_c2, nullptr);
    __syncthreads();

    // ---- L3: h3 = relu([c1|c2|c3] @ W3 + b3)  -> hi+lo ----
    acc[0] = {0,0,0,0}; acc[1] = {0,0,0,0};
    gemm16<8>(s_c1, 256, ws + WS_B3,           ct0, lane, acc);
    gemm16<4>(s_c2, 128, ws + WS_B3 +  8*4096, ct0, lane, acc);
    gemm16<1>(s_c3,  64, ws + WS_B3 + 12*4096, ct0, lane, acc);
    epi16(acc, out_b1, ct0, lane, s_h3h, s_h3l);
    __syncthreads();

    // ---- L4: h4 = relu(h3 @ W4 + b4)  (split) ----
    acc[0] = {0,0,0,0}; acc[1] = {0,0,0,0};
    gemm16s<4>(s_h3h, s_h3l, 128, ws + WS_B4, ws + WS_L4LO, ct0, lane, acc);
    epi16(acc, out_b2, ct0, lane, s_h4h, s_h4l);
    __syncthreads();

    // ---- L5: out = (h4 @ W5 + b5) * mask_pair  (split) ----
    acc[0] = {0,0,0,0}; acc[1] = {0,0,0,0};
    gemm16s<4>(s_h4h, s_h4l, 128, ws + WS_B5, ws + WS_L5LO, ct0, lane, acc);
    {
        const int rr = (lane >> 4) << 2;
        float mi = mask_atoms[ri*15 + 1];
#pragma unroll
        for (int ct = 0; ct < 2; ++ct){
            int col = (ct0 + ct)*16 + (lane & 15);
            float b = out_b3[col];
#pragma unroll
            for (int r = 0; r < 4; ++r){
                int m = rr + r;
                float mp = mi * mask_atoms[(rj0 + m)*15 + 1];
                out[((size_t)(ri*L_SEQ) + (size_t)(j0 + m))*128 + col] = (acc[ct][r] + b) * mp;
            }
        }
    }
}

extern "C" void kernel_launch(void* const* d_in, const int* in_sizes, int n_in,
                              void* d_out, int out_size, void* d_ws, size_t ws_size,
                              hipStream_t stream) {
    const int*   aa             = (const int*)  d_in[0];
    const int*   res_nb         = (const int*)  d_in[1];
    const int*   chain_nb       = (const int*)  d_in[2];
    const float* pos_atoms      = (const float*)d_in[3];
    const float* mask_atoms     = (const float*)d_in[4];
    const float* aa_embed_w     = (const float*)d_in[5];
    const float* relpos_embed_w = (const float*)d_in[6];
    const float* distcoef_w     = (const float*)d_in[7];
    const float* dist_w1        = (const float*)d_in[8];
    const float* dist_b1        = (const float*)d_in[9];
    const float* dist_w2        = (const float*)d_in[10];
    const float* dist_b2        = (const float*)d_in[11];
    const float* out_w1         = (const float*)d_in[12];
    const float* out_b1         = (const float*)d_in[13];
    const float* out_w2         = (const float*)d_in[14];
    const float* out_b2         = (const float*)d_in[15];
    const float* out_w3         = (const float*)d_in[16];
    const float* out_b3         = (const float*)d_in[17];
    float* out = (float*)d_out;
    u16* ws = (u16*)d_ws;

    hipLaunchKernelGGL(prep_w, dim3((WS_TOTAL + 255)/256), dim3(256), 0, stream,
                       dist_w1, dist_w2, out_w1, out_w2, out_w3, ws);

    const int nblocks = 2 * L_SEQ * (L_SEQ / TMP);   // 8192
    hipLaunchKernelGGL(rpe_mfma2, dim3(nblocks), dim3(256), 0, stream,
                       aa, res_nb, chain_nb, pos_atoms, mask_atoms,
                       aa_embed_w, relpos_embed_w, distcoef_w,
                       dist_b1, dist_b2, out_b1, out_b2, out_b3,
                       ws, out);
}

// Round 6
// 142.626 us; speedup vs baseline: 7.7577x; 1.5954x over previous
//
#include <hip/hip_runtime.h>
#include <math.h>

typedef __attribute__((ext_vector_type(8))) short bf16x8;
typedef __attribute__((ext_vector_type(4))) float f32x4;
typedef unsigned short u16;

#define L_SEQ 256
#define TMP 16
#define MFMA __builtin_amdgcn_mfma_f32_16x16x32_bf16

// ws element offsets (u16 elements). Packed B-fragment layout per layer:
// [kt][ct(8)][lane(64)][e(8)], elem = W[kt*32 + (lane>>4)*8 + e][ct*16 + (lane&15)]
#define WS_B1   0        // dist_w1: Kp=256 (K=225), 8 kt
#define WS_B2   32768    // dist_w2: Kp=128, 4 kt
#define WS_B3   49152    // out_w1:  Kp=416 (K=410), 13 kt
#define WS_B4   102400   // out_w2:  Kp=128
#define WS_B5   118784   // out_w3:  Kp=128
#define WS_L4LO 135168   // lo parts, out_w2
#define WS_L5LO 151552   // lo parts, out_w3
#define WS_TOTAL 167936  // u16 elements; softplus f32 table follows (435.6 KB more)
#define SP_N    108900   // 484*225

__device__ inline u16 f2bf(float f){
    unsigned u = __float_as_uint(f);
    unsigned r = (u + 0x7FFFu + ((u >> 16) & 1u)) >> 16;
    return (u16)r;
}
__device__ inline float bf2f(u16 h){ return __uint_as_float(((unsigned)h) << 16); }
__device__ inline int swz(int m, int k, int lda){ return m*lda + (k ^ ((m & 7) << 3)); }

struct F3 { float x, y, z; };
__device__ inline F3 f3sub(F3 a, F3 b){ return {a.x-b.x, a.y-b.y, a.z-b.z}; }
__device__ inline F3 f3cross(F3 a, F3 b){
    return {a.y*b.z - a.z*b.y, a.z*b.x - a.x*b.z, a.x*b.y - a.y*b.x};
}
__device__ inline float f3dot(F3 a, F3 b){ return a.x*b.x + a.y*b.y + a.z*b.z; }

__device__ inline float dihedral(F3 p0, F3 p1, F3 p2, F3 p3){
    F3 v0 = f3sub(p2, p1);
    F3 v1 = f3sub(p0, p1);
    F3 v2 = f3sub(p3, p2);
    F3 u1 = f3cross(v0, v1);
    F3 u2 = f3cross(v0, v2);
    float in1 = rsqrtf(f3dot(u1, u1) + 1e-10f);
    float in2 = rsqrtf(f3dot(u2, u2) + 1e-10f);
    F3 n1 = {u1.x*in1, u1.y*in1, u1.z*in1};
    F3 n2 = {u2.x*in2, u2.y*in2, u2.z*in2};
    float s = f3dot(f3cross(v0, n1), n2);
    float sgn = (s > 0.f) ? 1.f : ((s < 0.f) ? -1.f : 0.f);
    float c = f3dot(n1, n2);
    c = fminf(fmaxf(c, -1.f + 1e-7f), 1.f - 1e-7f);
    return sgn * acosf(c);
}

// ---------------- weight split+pack prep kernel (R4/R5-proven layout) ----------------
__global__ __launch_bounds__(256)
void prep_w(const float* __restrict__ w1, const float* __restrict__ w2,
            const float* __restrict__ w3, const float* __restrict__ w4,
            const float* __restrict__ w5, u16* __restrict__ ws)
{
    int idx = blockIdx.x * 256 + threadIdx.x;
    if (idx >= WS_TOTAL) return;
    const float* W; int Kreal, rel; bool lo = false;
    if      (idx < WS_B2)   { W = w1; Kreal = 225; rel = idx; }
    else if (idx < WS_B3)   { W = w2; Kreal = 128; rel = idx - WS_B2; }
    else if (idx < WS_B4)   { W = w3; Kreal = 410; rel = idx - WS_B3; }
    else if (idx < WS_B5)   { W = w4; Kreal = 128; rel = idx - WS_B4; }
    else if (idx < WS_L4LO) { W = w5; Kreal = 128; rel = idx - WS_B5; }
    else if (idx < WS_L5LO) { W = w4; Kreal = 128; rel = idx - WS_L4LO; lo = true; }
    else                    { W = w5; Kreal = 128; rel = idx - WS_L5LO; lo = true; }
    int e = rel & 7, lane = (rel >> 3) & 63, ct = (rel >> 9) & 7, kt = rel >> 12;
    int k = kt*32 + ((lane >> 4) << 3) + e;
    int col = ct*16 + (lane & 15);
    float v = (k < Kreal) ? W[k*128 + col] : 0.f;
    u16 h = f2bf(v);
    ws[idx] = lo ? f2bf(v - bf2f(h)) : h;
}

// softplus(distcoef) table: 484 aa-pairs x 225 atom-pairs, f32
__global__ __launch_bounds__(256)
void prep_sp(const float* __restrict__ dc, float* __restrict__ sp)
{
    int i = blockIdx.x * 256 + threadIdx.x;
    if (i < SP_N){
        float cw = dc[i];
        sp[i] = fmaxf(cw, 0.f) + log1pf(expf(-fabsf(cw)));
    }
}

// ---------------- single-m-tile MFMA gemm (R4/R5-PROVEN) ----------------
template<int T>
__device__ inline void gemm16(const u16* __restrict__ A, int lda,
                              const u16* __restrict__ B,
                              int ct0, int lane, f32x4 acc[2])
{
    const int r15 = lane & 15;
    const int koff = (lane >> 4) << 3;
    const int sx = (r15 & 7) << 3;
    const u16* ap = A + r15*lda;
#pragma unroll
    for (int kt = 0; kt < T; ++kt){
        int kk = ((kt << 5) + koff) ^ sx;
        bf16x8 a = *(const bf16x8*)(ap + kk);
        const u16* bp = B + (((kt*8 + ct0)*64 + lane) << 3);
        bf16x8 b0 = *(const bf16x8*)(bp);
        bf16x8 b1 = *(const bf16x8*)(bp + 512);
        acc[0] = MFMA(a, b0, acc[0], 0, 0, 0);
        acc[1] = MFMA(a, b1, acc[1], 0, 0, 0);
    }
}

// split variant: acc += Ahi*Bhi + Ahi*Blo + Alo*Bhi  (R5-proven)
template<int T>
__device__ inline void gemm16s(const u16* __restrict__ Ah, const u16* __restrict__ Al, int lda,
                               const u16* __restrict__ Bh, const u16* __restrict__ Bl,
                               int ct0, int lane, f32x4 acc[2])
{
    const int r15 = lane & 15;
    const int koff = (lane >> 4) << 3;
    const int sx = (r15 & 7) << 3;
    const u16* ahp = Ah + r15*lda;
    const u16* alp = Al + r15*lda;
#pragma unroll
    for (int kt = 0; kt < T; ++kt){
        int kk = ((kt << 5) + koff) ^ sx;
        bf16x8 ah = *(const bf16x8*)(ahp + kk);
        bf16x8 al = *(const bf16x8*)(alp + kk);
        const int bo = ((kt*8 + ct0)*64 + lane) << 3;
#pragma unroll
        for (int ct = 0; ct < 2; ++ct){
            bf16x8 bh = *(const bf16x8*)(Bh + bo + ct*512);
            bf16x8 bl = *(const bf16x8*)(Bl + bo + ct*512);
            acc[ct] = MFMA(ah, bh, acc[ct], 0, 0, 0);
            acc[ct] = MFMA(ah, bl, acc[ct], 0, 0, 0);
            acc[ct] = MFMA(al, bh, acc[ct], 0, 0, 0);
        }
    }
}

// epilogue: bias+relu -> swizzled bf16 LDS (hi, optional lo). R4/R5-proven mapping.
__device__ inline void epi16(f32x4 acc[2], const float* __restrict__ bias,
                             int ct0, int lane, u16* Dhi, u16* Dlo)
{
    const int rr = (lane >> 4) << 2;
#pragma unroll
    for (int ct = 0; ct < 2; ++ct){
        int col = (ct0 + ct)*16 + (lane & 15);
        float b = bias[col];
#pragma unroll
        for (int r = 0; r < 4; ++r){
            int m = rr + r;
            int idx = m*128 + (col ^ ((m & 7) << 3));
            float v = fmaxf(acc[ct][r] + b, 0.f);
            u16 h = f2bf(v);
            Dhi[idx] = h;
            if (Dlo) Dlo[idx] = f2bf(v - bf2f(h));
        }
    }
}

// ---------------- main fused kernel ----------------
__global__ __launch_bounds__(256, 5)
void rpe_mfma3(const int* __restrict__ aa, const int* __restrict__ res_nb,
               const int* __restrict__ chain_nb,
               const float* __restrict__ pos_atoms, const float* __restrict__ mask_atoms,
               const float* __restrict__ aa_embed_w, const float* __restrict__ relpos_embed_w,
               const float* __restrict__ sp_table,
               const float* __restrict__ dist_b1, const float* __restrict__ dist_b2,
               const float* __restrict__ out_b1, const float* __restrict__ out_b2,
               const float* __restrict__ out_b3,
               const u16* __restrict__ ws, float* __restrict__ out)
{
    const int t = threadIdx.x;
    const int bid = blockIdx.x;
    const int n  = bid >> 12;
    const int i  = (bid >> 4) & 255;
    const int j0 = (bid & 15) << 4;
    const int ri = n*L_SEQ + i;
    const int rj0 = n*L_SEQ + j0;

    // LDS budget ~30.3 KB -> 5 blocks/CU.
    __shared__ __align__(16) u16   s_g[TMP*256];    // gauss bf16 swz  | L3+: h3h @0, h3l @2048
    __shared__ __align__(16) u16   s_c1[TMP*256];   // aapair|relpos   | L4+: h4h @0, h4l @2048
    __shared__ __align__(16) u16   s_c2[TMP*128];   // dist feat bf16
    __shared__ __align__(16) u16   s_c3[TMP*64];    // dihed bf16 (26+pad)
    __shared__ __align__(16) u16   s_h1[TMP*128];   // h1 bf16
    __shared__ __align__(16) float s_stage[1024];   // staging, dead after feature phase (not aliased)
    __shared__ int   s_aap[TMP];
    __shared__ int   s_rp[TMP];
    __shared__ float s_same[TMP];
    __shared__ float s_mpair[TMP];

    u16* s_h3h = s_g;          u16* s_h3l = s_g  + 2048;   // alias: s_g dead after L1
    u16* s_h4h = s_c1;         u16* s_h4l = s_c1 + 2048;   // alias: s_c1 dead after L3 gemm

    float* u_posj  = s_stage;          // [16*45)
    float* u_posi  = s_stage + 720;    // 45
    float* u_maskj = s_stage + 768;    // 240
    float* u_maski = s_stage + 1008;   // 15

    // ---- stage residue data ----
    for (int idx = t; idx < TMP*45; idx += 256) u_posj[idx] = pos_atoms[rj0*45 + idx];
    if (t < 45) u_posi[t] = pos_atoms[ri*45 + t];
    for (int idx = t; idx < TMP*15; idx += 256) u_maskj[idx] = mask_atoms[rj0*15 + idx];
    if (t >= 64 && t < 79) u_maski[t - 64] = mask_atoms[ri*15 + (t - 64)];
    if (t >= 96 && t < 96 + TMP){
        int m = t - 96, rj = rj0 + m;
        s_aap[m] = aa[ri]*22 + aa[rj];
        int d = res_nb[ri] - res_nb[rj];
        d = min(max(d, -32), 32);
        s_rp[m] = d + 32;
        s_same[m] = (chain_nb[ri] == chain_nb[rj]) ? 1.f : 0.f;
    }
    __syncthreads();

    if (t < TMP) s_mpair[t] = u_maski[1] * u_maskj[t*15 + 1];   // BB_CA = 1

    // ---- gaussian distance features: k = t (fixed per thread), loop over m ----
    {
        const int kg = t;                       // 0..255; active if < 225
        const bool act = kg < 225;
        int ga = 0, gb = 0;
        float pix = 0, piy = 0, piz = 0, mi_a = 0;
        if (act){
            ga = kg / 15; gb = kg - ga*15;      // hoisted: one magic-mul, once
            pix = u_posi[ga*3+0]; piy = u_posi[ga*3+1]; piz = u_posi[ga*3+2];
            mi_a = u_maski[ga];
        }
#pragma unroll 4
        for (int m = 0; m < TMP; ++m){
            float g = 0.f;
            if (act){
                float dx = pix - u_posj[m*45 + gb*3+0];
                float dy = piy - u_posj[m*45 + gb*3+1];
                float dz = piz - u_posj[m*45 + gb*3+2];
                float d2 = (dx*dx + dy*dy + dz*dz + 1e-10f) * 0.01f;
                float c = sp_table[s_aap[m]*225 + kg];
                g = expf(-c*d2) * mi_a * u_maskj[m*15 + gb];
            }
            s_g[swz(m, kg, 256)] = f2bf(g);
        }
    }

    // ---- embedding gathers (bf16, swizzled) ----
    {
        const int c = t & 127;
        const int mb = t >> 7;                  // 0 or 1
#pragma unroll
        for (int it = 0; it < 8; ++it){
            int m = mb + it*2;
            s_c1[swz(m, c,       256)] = f2bf(aa_embed_w[s_aap[m]*128 + c]);
            s_c1[swz(m, 128 + c, 256)] = f2bf(s_same[m] * relpos_embed_w[s_rp[m]*128 + c]);
        }
    }

    // ---- dihedral features (bf16 into s_c3) ----
    if (t < 2*TMP){
        int m = t >> 1, w = t & 1;
        F3 P0, P1, P2, P3;
        if (w == 0){   // phi: pC_i, pN_j, pCA_j, pC_j
            P0 = {u_posi[6],  u_posi[7],  u_posi[8]};
            P1 = {u_posj[m*45+0], u_posj[m*45+1], u_posj[m*45+2]};
            P2 = {u_posj[m*45+3], u_posj[m*45+4], u_posj[m*45+5]};
            P3 = {u_posj[m*45+6], u_posj[m*45+7], u_posj[m*45+8]};
        } else {       // psi: pN_i, pCA_i, pC_i, pN_j
            P0 = {u_posi[0], u_posi[1], u_posi[2]};
            P1 = {u_posi[3], u_posi[4], u_posi[5]};
            P2 = {u_posi[6], u_posi[7], u_posi[8]};
            P3 = {u_posj[m*45+0], u_posj[m*45+1], u_posj[m*45+2]};
        }
        float x = dihedral(P0, P1, P2, P3);
        int kb = w*13;
        s_c3[swz(m, kb+0,  64)] = f2bf(x);
        s_c3[swz(m, kb+1,  64)] = f2bf(sinf(x));
        s_c3[swz(m, kb+2,  64)] = f2bf(sinf(2.f*x));
        s_c3[swz(m, kb+3,  64)] = f2bf(sinf(3.f*x));
        s_c3[swz(m, kb+4,  64)] = f2bf(sinf(x));
        s_c3[swz(m, kb+5,  64)] = f2bf(sinf(0.5f*x));
        s_c3[swz(m, kb+6,  64)] = f2bf(sinf(x*(1.f/3.f)));
        s_c3[swz(m, kb+7,  64)] = f2bf(cosf(x));
        s_c3[swz(m, kb+8,  64)] = f2bf(cosf(2.f*x));
        s_c3[swz(m, kb+9,  64)] = f2bf(cosf(3.f*x));
        s_c3[swz(m, kb+10, 64)] = f2bf(cosf(x));
        s_c3[swz(m, kb+11, 64)] = f2bf(cosf(0.5f*x));
        s_c3[swz(m, kb+12, 64)] = f2bf(cosf(x*(1.f/3.f)));
    }
    {   // pad dihed cols 26..63 with zeros: 16*38 = 608 slots
        for (int idx = t; idx < TMP*38; idx += 256){ int m = idx/38; s_c3[swz(m, 26 + idx - m*38, 64)] = 0; }
    }
    __syncthreads();

    const int lane = t & 63;
    const int ct0 = (t >> 6) * 2;   // wave -> 2 col-tiles

    // ---- L1: h1 = relu(g @ W1 + b1) ----
    f32x4 acc[2];
    acc[0] = {0,0,0,0}; acc[1] = {0,0,0,0};
    gemm16<8>(s_g, 256, ws + WS_B1, ct0, lane, acc);
    __syncthreads();                 // ensure all reads of s_g complete before epi writes alias region? (h1 is separate; barrier keeps phase discipline)
    epi16(acc, dist_b1, ct0, lane, s_h1, nullptr);
    __syncthreads();

    // ---- L2: feat_dist = relu(h1 @ W2 + b2) ----
    acc[0] = {0,0,0,0}; acc[1] = {0,0,0,0};
    gemm16<4>(s_h1, 128, ws + WS_B2, ct0, lane, acc);
    epi16(acc, dist_b2, ct0, lane, s_c2, nullptr);
    __syncthreads();

    // ---- L3: h3 = relu([c1|c2|c3] @ W3 + b3)  -> hi+lo (writes alias s_g; s_g dead) ----
    acc[0] = {0,0,0,0}; acc[1] = {0,0,0,0};
    gemm16<8>(s_c1, 256, ws + WS_B3,           ct0, lane, acc);
    gemm16<4>(s_c2, 128, ws + WS_B3 +  8*4096, ct0, lane, acc);
    gemm16<1>(s_c3,  64, ws + WS_B3 + 12*4096, ct0, lane, acc);
    __syncthreads();                 // all c1 reads done before h4 aliases it next phase; also orders h3 writes
    epi16(acc, out_b1, ct0, lane, s_h3h, s_h3l);
    __syncthreads();

    // ---- L4: h4 = relu(h3 @ W4 + b4)  (split; writes alias s_c1; c1 dead) ----
    acc[0] = {0,0,0,0}; acc[1] = {0,0,0,0};
    gemm16s<4>(s_h3h, s_h3l, 128, ws + WS_B4, ws + WS_L4LO, ct0, lane, acc);
    __syncthreads();
    epi16(acc, out_b2, ct0, lane, s_h4h, s_h4l);
    __syncthreads();

    // ---- L5: out = (h4 @ W5 + b5) * mask_pair  (split) ----
    acc[0] = {0,0,0,0}; acc[1] = {0,0,0,0};
    gemm16s<4>(s_h4h, s_h4l, 128, ws + WS_B5, ws + WS_L5LO, ct0, lane, acc);
    {
        const int rr = (lane >> 4) << 2;
#pragma unroll
        for (int ct = 0; ct < 2; ++ct){
            int col = (ct0 + ct)*16 + (lane & 15);
            float b = out_b3[col];
#pragma unroll
            for (int r = 0; r < 4; ++r){
                int m = rr + r;
                out[((size_t)(ri*L_SEQ) + (size_t)(j0 + m))*128 + col] = (acc[ct][r] + b) * s_mpair[m];
            }
        }
    }
}

extern "C" void kernel_launch(void* const* d_in, const int* in_sizes, int n_in,
                              void* d_out, int out_size, void* d_ws, size_t ws_size,
                              hipStream_t stream) {
    const int*   aa             = (const int*)  d_in[0];
    const int*   res_nb         = (const int*)  d_in[1];
    const int*   chain_nb       = (const int*)  d_in[2];
    const float* pos_atoms      = (const float*)d_in[3];
    const float* mask_atoms     = (const float*)d_in[4];
    const float* aa_embed_w     = (const float*)d_in[5];
    const float* relpos_embed_w = (const float*)d_in[6];
    const float* distcoef_w     = (const float*)d_in[7];
    const float* dist_w1        = (const float*)d_in[8];
    const float* dist_b1        = (const float*)d_in[9];
    const float* dist_w2        = (const float*)d_in[10];
    const float* dist_b2        = (const float*)d_in[11];
    const float* out_w1         = (const float*)d_in[12];
    const float* out_b1         = (const float*)d_in[13];
    const float* out_w2         = (const float*)d_in[14];
    const float* out_b2         = (const float*)d_in[15];
    const float* out_w3         = (const float*)d_in[16];
    const float* out_b3         = (const float*)d_in[17];
    float* out = (float*)d_out;
    u16* ws = (u16*)d_ws;
    float* sp = (float*)(ws + WS_TOTAL);   // byte offset 335872, 4B-aligned

    hipLaunchKernelGGL(prep_w, dim3((WS_TOTAL + 255)/256), dim3(256), 0, stream,
                       dist_w1, dist_w2, out_w1, out_w2, out_w3, ws);
    hipLaunchKernelGGL(prep_sp, dim3((SP_N + 255)/256), dim3(256), 0, stream,
                       distcoef_w, sp);

    const int nblocks = 2 * L_SEQ * (L_SEQ / TMP);   // 8192
    hipLaunchKernelGGL(rpe_mfma3, dim3(nblocks), dim3(256), 0, stream,
                       aa, res_nb, chain_nb, pos_atoms, mask_atoms,
                       aa_embed_w, relpos_embed_w, sp,
                       dist_b1, dist_b2, out_b1, out_b2, out_b3,
                       ws, out);
}

// Round 7
// 141.582 us; speedup vs baseline: 7.8149x; 1.0074x over previous
//
#include <hip/hip_runtime.h>
#include <math.h>

typedef __attribute__((ext_vector_type(8))) short bf16x8;
typedef __attribute__((ext_vector_type(4))) float f32x4;
typedef unsigned short u16;

#define L_SEQ 256
#define TMP 16      // pairs per wave-group
#define MFMA __builtin_amdgcn_mfma_f32_16x16x32_bf16

// ws element offsets (u16 elements). Packed B-fragment layout per layer:
// [kt][ct(8)][lane(64)][e(8)], elem = W[kt*32 + (lane>>4)*8 + e][ct*16 + (lane&15)]
#define WS_B1   0        // dist_w1: Kp=256 (K=225), 8 kt
#define WS_B2   32768    // dist_w2: Kp=128, 4 kt
#define WS_B3   49152    // out_w1:  Kp=416 (K=410), 13 kt
#define WS_B4   102400   // out_w2:  Kp=128
#define WS_B5   118784   // out_w3:  Kp=128
#define WS_L4LO 135168   // lo parts, out_w2
#define WS_L5LO 151552   // lo parts, out_w3
#define WS_TOTAL 167936  // u16 elements; softplus f32 table follows
#define SP_N    108900   // 484*225

__device__ inline u16 f2bf(float f){
    unsigned u = __float_as_uint(f);
    unsigned r = (u + 0x7FFFu + ((u >> 16) & 1u)) >> 16;
    return (u16)r;
}
__device__ inline float bf2f(u16 h){ return __uint_as_float(((unsigned)h) << 16); }
__device__ inline int swz(int m, int k, int lda){ return m*lda + (k ^ ((m & 7) << 3)); }

struct F3 { float x, y, z; };
__device__ inline F3 f3sub(F3 a, F3 b){ return {a.x-b.x, a.y-b.y, a.z-b.z}; }
__device__ inline F3 f3cross(F3 a, F3 b){
    return {a.y*b.z - a.z*b.y, a.z*b.x - a.x*b.z, a.x*b.y - a.y*b.x};
}
__device__ inline float f3dot(F3 a, F3 b){ return a.x*b.x + a.y*b.y + a.z*b.z; }

__device__ inline float dihedral(F3 p0, F3 p1, F3 p2, F3 p3){
    F3 v0 = f3sub(p2, p1);
    F3 v1 = f3sub(p0, p1);
    F3 v2 = f3sub(p3, p2);
    F3 u1 = f3cross(v0, v1);
    F3 u2 = f3cross(v0, v2);
    float in1 = rsqrtf(f3dot(u1, u1) + 1e-10f);
    float in2 = rsqrtf(f3dot(u2, u2) + 1e-10f);
    F3 n1 = {u1.x*in1, u1.y*in1, u1.z*in1};
    F3 n2 = {u2.x*in2, u2.y*in2, u2.z*in2};
    float s = f3dot(f3cross(v0, n1), n2);
    float sgn = (s > 0.f) ? 1.f : ((s < 0.f) ? -1.f : 0.f);
    float c = f3dot(n1, n2);
    c = fminf(fmaxf(c, -1.f + 1e-7f), 1.f - 1e-7f);
    return sgn * acosf(c);
}

// ---------------- weight split+pack prep kernel (R4/R5-proven layout) ----------------
__global__ __launch_bounds__(256)
void prep_w(const float* __restrict__ w1, const float* __restrict__ w2,
            const float* __restrict__ w3, const float* __restrict__ w4,
            const float* __restrict__ w5, u16* __restrict__ ws)
{
    int idx = blockIdx.x * 256 + threadIdx.x;
    if (idx >= WS_TOTAL) return;
    const float* W; int Kreal, rel; bool lo = false;
    if      (idx < WS_B2)   { W = w1; Kreal = 225; rel = idx; }
    else if (idx < WS_B3)   { W = w2; Kreal = 128; rel = idx - WS_B2; }
    else if (idx < WS_B4)   { W = w3; Kreal = 410; rel = idx - WS_B3; }
    else if (idx < WS_B5)   { W = w4; Kreal = 128; rel = idx - WS_B4; }
    else if (idx < WS_L4LO) { W = w5; Kreal = 128; rel = idx - WS_B5; }
    else if (idx < WS_L5LO) { W = w4; Kreal = 128; rel = idx - WS_L4LO; lo = true; }
    else                    { W = w5; Kreal = 128; rel = idx - WS_L5LO; lo = true; }
    int e = rel & 7, lane = (rel >> 3) & 63, ct = (rel >> 9) & 7, kt = rel >> 12;
    int k = kt*32 + ((lane >> 4) << 3) + e;
    int col = ct*16 + (lane & 15);
    float v = (k < Kreal) ? W[k*128 + col] : 0.f;
    u16 h = f2bf(v);
    ws[idx] = lo ? f2bf(v - bf2f(h)) : h;
}

// softplus(distcoef) table: 484 aa-pairs x 225 atom-pairs, f32
__global__ __launch_bounds__(256)
void prep_sp(const float* __restrict__ dc, float* __restrict__ sp)
{
    int i = blockIdx.x * 256 + threadIdx.x;
    if (i < SP_N){
        float cw = dc[i];
        sp[i] = fmaxf(cw, 0.f) + log1pf(expf(-fabsf(cw)));
    }
}

// ---------------- single-m-tile MFMA gemm (R4/R5/R6-PROVEN) ----------------
template<int T>
__device__ inline void gemm16(const u16* __restrict__ A, int lda,
                              const u16* __restrict__ B,
                              int ct0, int lane, f32x4 acc[2])
{
    const int r15 = lane & 15;
    const int koff = (lane >> 4) << 3;
    const int sx = (r15 & 7) << 3;
    const u16* ap = A + r15*lda;
#pragma unroll
    for (int kt = 0; kt < T; ++kt){
        int kk = ((kt << 5) + koff) ^ sx;
        bf16x8 a = *(const bf16x8*)(ap + kk);
        const u16* bp = B + (((kt*8 + ct0)*64 + lane) << 3);
        bf16x8 b0 = *(const bf16x8*)(bp);
        bf16x8 b1 = *(const bf16x8*)(bp + 512);
        acc[0] = MFMA(a, b0, acc[0], 0, 0, 0);
        acc[1] = MFMA(a, b1, acc[1], 0, 0, 0);
    }
}

// split variant: acc += Ahi*Bhi + Ahi*Blo + Alo*Bhi  (R5/R6-proven)
template<int T>
__device__ inline void gemm16s(const u16* __restrict__ Ah, const u16* __restrict__ Al, int lda,
                               const u16* __restrict__ Bh, const u16* __restrict__ Bl,
                               int ct0, int lane, f32x4 acc[2])
{
    const int r15 = lane & 15;
    const int koff = (lane >> 4) << 3;
    const int sx = (r15 & 7) << 3;
    const u16* ahp = Ah + r15*lda;
    const u16* alp = Al + r15*lda;
#pragma unroll
    for (int kt = 0; kt < T; ++kt){
        int kk = ((kt << 5) + koff) ^ sx;
        bf16x8 ah = *(const bf16x8*)(ahp + kk);
        bf16x8 al = *(const bf16x8*)(alp + kk);
        const int bo = ((kt*8 + ct0)*64 + lane) << 3;
#pragma unroll
        for (int ct = 0; ct < 2; ++ct){
            bf16x8 bh = *(const bf16x8*)(Bh + bo + ct*512);
            bf16x8 bl = *(const bf16x8*)(Bl + bo + ct*512);
            acc[ct] = MFMA(ah, bh, acc[ct], 0, 0, 0);
            acc[ct] = MFMA(ah, bl, acc[ct], 0, 0, 0);
            acc[ct] = MFMA(al, bh, acc[ct], 0, 0, 0);
        }
    }
}

// epilogue: bias+relu -> swizzled bf16 LDS (hi, optional lo). Proven mapping.
__device__ inline void epi16(f32x4 acc[2], const float* __restrict__ bias,
                             int ct0, int lane, u16* Dhi, u16* Dlo)
{
    const int rr = (lane >> 4) << 2;
#pragma unroll
    for (int ct = 0; ct < 2; ++ct){
        int col = (ct0 + ct)*16 + (lane & 15);
        float b = bias[col];
#pragma unroll
        for (int r = 0; r < 4; ++r){
            int m = rr + r;
            int idx = m*128 + (col ^ ((m & 7) << 3));
            float v = fmaxf(acc[ct][r] + b, 0.f);
            u16 h = f2bf(v);
            Dhi[idx] = h;
            if (Dlo) Dlo[idx] = f2bf(v - bf2f(h));
        }
    }
}

// ---------------- main fused kernel: 512 threads, two independent 16-pair groups ----------------
__global__ __launch_bounds__(512, 6)
void rpe_mfma4(const int* __restrict__ aa, const int* __restrict__ res_nb,
               const int* __restrict__ chain_nb,
               const float* __restrict__ pos_atoms, const float* __restrict__ mask_atoms,
               const float* __restrict__ aa_embed_w, const float* __restrict__ relpos_embed_w,
               const float* __restrict__ sp_table,
               const float* __restrict__ dist_b1, const float* __restrict__ dist_b2,
               const float* __restrict__ out_b1, const float* __restrict__ out_b2,
               const float* __restrict__ out_b3,
               const u16* __restrict__ ws, float* __restrict__ out)
{
    const int t  = threadIdx.x;
    const int g  = t >> 8;          // wave-group 0/1
    const int tl = t & 255;         // thread-in-group
    const int bid = blockIdx.x;     // 0..4095
    const int n  = bid >> 11;
    const int i  = (bid >> 3) & 255;
    const int j0 = ((bid & 7) << 5) + g*16;
    const int ri = n*L_SEQ + i;
    const int rj0 = n*L_SEQ + j0;

    // per-group LDS; total ~53.8 KB -> 3 blocks/CU (24 waves = 75%)
    __shared__ __align__(16) u16 s_g[2][TMP*256];    // gauss | L3+: h3h @0, h3l @2048
    __shared__ __align__(16) u16 s_c1[2][TMP*256];   // aapair|relpos | L4+: h4h @0, h4l @2048
    __shared__ __align__(16) u16 s_c2[2][TMP*128];   // dist feat
    __shared__ __align__(16) u16 s_c3[2][TMP*64];    // dihed (26+pad)
    __shared__ __align__(16) u16 s_h1s[2][TMP*128];  // h1 bf16; ALIASED with f32 staging (dead by L1-epi)
    __shared__ int   s_aap[2][TMP];
    __shared__ int   s_rp[2][TMP];
    __shared__ float s_same[2][TMP];
    __shared__ float s_mpair[2][TMP];

    u16* h3h = s_g[g];    u16* h3l = s_g[g]  + 2048;
    u16* h4h = s_c1[g];   u16* h4l = s_c1[g] + 2048;
    u16* s_h1 = s_h1s[g];

    float* stage   = (float*)s_h1s[g];   // 1024 floats available
    float* u_posj  = stage;              // 720
    float* u_posi  = stage + 720;        // 45
    float* u_maskj = stage + 768;        // 240
    float* u_maski = stage + 1008;       // 15  (ends 1023)

    // ---- stage residue data (per group) ----
    for (int idx = tl; idx < TMP*45; idx += 256) u_posj[idx] = pos_atoms[rj0*45 + idx];
    if (tl < 45) u_posi[tl] = pos_atoms[ri*45 + tl];
    for (int idx = tl; idx < TMP*15; idx += 256) u_maskj[idx] = mask_atoms[rj0*15 + idx];
    if (tl >= 64 && tl < 79) u_maski[tl - 64] = mask_atoms[ri*15 + (tl - 64)];
    if (tl >= 96 && tl < 96 + TMP){
        int m = tl - 96, rj = rj0 + m;
        s_aap[g][m] = aa[ri]*22 + aa[rj];
        int d = res_nb[ri] - res_nb[rj];
        d = min(max(d, -32), 32);
        s_rp[g][m] = d + 32;
        s_same[g][m] = (chain_nb[ri] == chain_nb[rj]) ? 1.f : 0.f;
    }
    __syncthreads();   // B1: staging complete

    if (tl < TMP) s_mpair[g][tl] = u_maski[1] * u_maskj[tl*15 + 1];   // BB_CA = 1

    // ---- gaussian distance features: k = tl fixed per thread, loop over m ----
    {
        const int kg = tl;                      // 0..255; active if < 225
        const bool act = kg < 225;
        int ga = 0, gb = 0;
        float pix = 0, piy = 0, piz = 0, mi_a = 0;
        if (act){
            ga = kg / 15; gb = kg - ga*15;
            pix = u_posi[ga*3+0]; piy = u_posi[ga*3+1]; piz = u_posi[ga*3+2];
            mi_a = u_maski[ga];
        }
#pragma unroll 4
        for (int m = 0; m < TMP; ++m){
            float gv = 0.f;
            if (act){
                float dx = pix - u_posj[m*45 + gb*3+0];
                float dy = piy - u_posj[m*45 + gb*3+1];
                float dz = piz - u_posj[m*45 + gb*3+2];
                float d2 = (dx*dx + dy*dy + dz*dz + 1e-10f) * 0.01f;
                float c = sp_table[s_aap[g][m]*225 + kg];
                gv = expf(-c*d2) * mi_a * u_maskj[m*15 + gb];
            }
            s_g[g][swz(m, kg, 256)] = f2bf(gv);
        }
    }

    // ---- embedding gathers (bf16, swizzled) ----
    {
        const int c = tl & 127;
        const int mb = tl >> 7;                 // 0 or 1
#pragma unroll
        for (int it = 0; it < 8; ++it){
            int m = mb + it*2;
            s_c1[g][swz(m, c,       256)] = f2bf(aa_embed_w[s_aap[g][m]*128 + c]);
            s_c1[g][swz(m, 128 + c, 256)] = f2bf(s_same[g][m] * relpos_embed_w[s_rp[g][m]*128 + c]);
        }
    }

    // ---- dihedral features (bf16 into s_c3) ----
    if (tl < 2*TMP){
        int m = tl >> 1, w = tl & 1;
        F3 P0, P1, P2, P3;
        if (w == 0){   // phi: pC_i, pN_j, pCA_j, pC_j
            P0 = {u_posi[6],  u_posi[7],  u_posi[8]};
            P1 = {u_posj[m*45+0], u_posj[m*45+1], u_posj[m*45+2]};
            P2 = {u_posj[m*45+3], u_posj[m*45+4], u_posj[m*45+5]};
            P3 = {u_posj[m*45+6], u_posj[m*45+7], u_posj[m*45+8]};
        } else {       // psi: pN_i, pCA_i, pC_i, pN_j
            P0 = {u_posi[0], u_posi[1], u_posi[2]};
            P1 = {u_posi[3], u_posi[4], u_posi[5]};
            P2 = {u_posi[6], u_posi[7], u_posi[8]};
            P3 = {u_posj[m*45+0], u_posj[m*45+1], u_posj[m*45+2]};
        }
        float x = dihedral(P0, P1, P2, P3);
        int kb = w*13;
        u16* c3 = s_c3[g];
        c3[swz(m, kb+0,  64)] = f2bf(x);
        c3[swz(m, kb+1,  64)] = f2bf(sinf(x));
        c3[swz(m, kb+2,  64)] = f2bf(sinf(2.f*x));
        c3[swz(m, kb+3,  64)] = f2bf(sinf(3.f*x));
        c3[swz(m, kb+4,  64)] = f2bf(sinf(x));
        c3[swz(m, kb+5,  64)] = f2bf(sinf(0.5f*x));
        c3[swz(m, kb+6,  64)] = f2bf(sinf(x*(1.f/3.f)));
        c3[swz(m, kb+7,  64)] = f2bf(cosf(x));
        c3[swz(m, kb+8,  64)] = f2bf(cosf(2.f*x));
        c3[swz(m, kb+9,  64)] = f2bf(cosf(3.f*x));
        c3[swz(m, kb+10, 64)] = f2bf(cosf(x));
        c3[swz(m, kb+11, 64)] = f2bf(cosf(0.5f*x));
        c3[swz(m, kb+12, 64)] = f2bf(cosf(x*(1.f/3.f)));
    }
    for (int idx = tl; idx < TMP*38; idx += 256){ int m = idx/38; s_c3[g][swz(m, 26 + idx - m*38, 64)] = 0; }
    __syncthreads();   // B2: features complete (incl. all staging reads)

    const int lane = t & 63;
    const int ct0 = ((t >> 6) & 3) * 2;   // wave-in-group -> 2 col-tiles

    // ---- L1: h1 = relu(g @ W1 + b1) ----
    f32x4 acc[2];
    acc[0] = {0,0,0,0}; acc[1] = {0,0,0,0};
    gemm16<8>(s_g[g], 256, ws + WS_B1, ct0, lane, acc);
    epi16(acc, dist_b1, ct0, lane, s_h1, nullptr);   // h1 overwrites dead staging
    __syncthreads();   // B3

    // ---- L2: feat_dist = relu(h1 @ W2 + b2) ----
    acc[0] = {0,0,0,0}; acc[1] = {0,0,0,0};
    gemm16<4>(s_h1, 128, ws + WS_B2, ct0, lane, acc);
    epi16(acc, dist_b2, ct0, lane, s_c2[g], nullptr);
    __syncthreads();   // B4

    // ---- L3: h3 = relu([c1|c2|c3] @ W3 + b3) -> hi+lo (aliases s_g; dead since L1) ----
    acc[0] = {0,0,0,0}; acc[1] = {0,0,0,0};
    gemm16<8>(s_c1[g], 256, ws + WS_B3,           ct0, lane, acc);
    gemm16<4>(s_c2[g], 128, ws + WS_B3 +  8*4096, ct0, lane, acc);
    gemm16<1>(s_c3[g],  64, ws + WS_B3 + 12*4096, ct0, lane, acc);
    epi16(acc, out_b1, ct0, lane, h3h, h3l);
    __syncthreads();   // B5 (also separates c1 reads from L4-epi c1-alias writes)

    // ---- L4: h4 = relu(h3 @ W4 + b4) (split; aliases s_c1) ----
    acc[0] = {0,0,0,0}; acc[1] = {0,0,0,0};
    gemm16s<4>(h3h, h3l, 128, ws + WS_B4, ws + WS_L4LO, ct0, lane, acc);
    epi16(acc, out_b2, ct0, lane, h4h, h4l);
    __syncthreads();   // B6

    // ---- L5: out = (h4 @ W5 + b5) * mask_pair (split) ----
    acc[0] = {0,0,0,0}; acc[1] = {0,0,0,0};
    gemm16s<4>(h4h, h4l, 128, ws + WS_B5, ws + WS_L5LO, ct0, lane, acc);
    {
        const int rr = (lane >> 4) << 2;
#pragma unroll
        for (int ct = 0; ct < 2; ++ct){
            int col = (ct0 + ct)*16 + (lane & 15);
            float b = out_b3[col];
#pragma unroll
            for (int r = 0; r < 4; ++r){
                int m = rr + r;
                out[((size_t)(ri*L_SEQ) + (size_t)(j0 + m))*128 + col] = (acc[ct][r] + b) * s_mpair[g][m];
            }
        }
    }
}

extern "C" void kernel_launch(void* const* d_in, const int* in_sizes, int n_in,
                              void* d_out, int out_size, void* d_ws, size_t ws_size,
                              hipStream_t stream) {
    const int*   aa             = (const int*)  d_in[0];
    const int*   res_nb         = (const int*)  d_in[1];
    const int*   chain_nb       = (const int*)  d_in[2];
    const float* pos_atoms      = (const float*)d_in[3];
    const float* mask_atoms     = (const float*)d_in[4];
    const float* aa_embed_w     = (const float*)d_in[5];
    const float* relpos_embed_w = (const float*)d_in[6];
    const float* distcoef_w     = (const float*)d_in[7];
    const float* dist_w1        = (const float*)d_in[8];
    const float* dist_b1        = (const float*)d_in[9];
    const float* dist_w2        = (const float*)d_in[10];
    const float* dist_b2        = (const float*)d_in[11];
    const float* out_w1         = (const float*)d_in[12];
    const float* out_b1         = (const float*)d_in[13];
    const float* out_w2         = (const float*)d_in[14];
    const float* out_b2         = (const float*)d_in[15];
    const float* out_w3         = (const float*)d_in[16];
    const float* out_b3         = (const float*)d_in[17];
    float* out = (float*)d_out;
    u16* ws = (u16*)d_ws;
    float* sp = (float*)(ws + WS_TOTAL);

    hipLaunchKernelGGL(prep_w, dim3((WS_TOTAL + 255)/256), dim3(256), 0, stream,
                       dist_w1, dist_w2, out_w1, out_w2, out_w3, ws);
    hipLaunchKernelGGL(prep_sp, dim3((SP_N + 255)/256), dim3(256), 0, stream,
                       distcoef_w, sp);

    const int nblocks = 2 * L_SEQ * (L_SEQ / 32);   // 4096 (32 pairs per block)
    hipLaunchKernelGGL(rpe_mfma4, dim3(nblocks), dim3(512), 0, stream,
                       aa, res_nb, chain_nb, pos_atoms, mask_atoms,
                       aa_embed_w, relpos_embed_w, sp,
                       dist_b1, dist_b2, out_b1, out_b2, out_b3,
                       ws, out);
}

// Round 8
// 120.172 us; speedup vs baseline: 9.2072x; 1.1782x over previous
//
#include <hip/hip_runtime.h>
#include <math.h>

typedef __attribute__((ext_vector_type(8))) short bf16x8;
typedef __attribute__((ext_vector_type(4))) float f32x4;
typedef unsigned short u16;

#define L_SEQ 256
#define TMP 16      // pairs per group
#define MFMA __builtin_amdgcn_mfma_f32_16x16x32_bf16

// ws element offsets (u16 elements). Packed B-fragment layout per layer:
// [kt][ct(8)][lane(64)][e(8)], elem = W[kt*32 + (lane>>4)*8 + e][ct*16 + (lane&15)]
#define WS_B1   0        // dist_w1: Kp=256 (K=225), 8 kt
#define WS_B2   32768    // dist_w2: Kp=128, 4 kt
#define WS_B3   49152    // out_w1:  Kp=416 (K=410), 13 kt
#define WS_B4   102400   // out_w2:  Kp=128
#define WS_B5   118784   // out_w3:  Kp=128
#define WS_L4LO 135168   // lo parts, out_w2
#define WS_L5LO 151552   // lo parts, out_w3
#define WS_TOTAL 167936  // u16 elements; softplus f32 table follows
#define SP_N    108900   // 484*225

__device__ inline u16 f2bf(float f){
    unsigned u = __float_as_uint(f);
    unsigned r = (u + 0x7FFFu + ((u >> 16) & 1u)) >> 16;
    return (u16)r;
}
__device__ inline float bf2f(u16 h){ return __uint_as_float(((unsigned)h) << 16); }
__device__ inline int swz(int m, int k, int lda){ return m*lda + (k ^ ((m & 7) << 3)); }

struct F3 { float x, y, z; };
__device__ inline F3 f3sub(F3 a, F3 b){ return {a.x-b.x, a.y-b.y, a.z-b.z}; }
__device__ inline F3 f3cross(F3 a, F3 b){
    return {a.y*b.z - a.z*b.y, a.z*b.x - a.x*b.z, a.x*b.y - a.y*b.x};
}
__device__ inline float f3dot(F3 a, F3 b){ return a.x*b.x + a.y*b.y + a.z*b.z; }

__device__ inline float dihedral(F3 p0, F3 p1, F3 p2, F3 p3){
    F3 v0 = f3sub(p2, p1);
    F3 v1 = f3sub(p0, p1);
    F3 v2 = f3sub(p3, p2);
    F3 u1 = f3cross(v0, v1);
    F3 u2 = f3cross(v0, v2);
    float in1 = rsqrtf(f3dot(u1, u1) + 1e-10f);
    float in2 = rsqrtf(f3dot(u2, u2) + 1e-10f);
    F3 n1 = {u1.x*in1, u1.y*in1, u1.z*in1};
    F3 n2 = {u2.x*in2, u2.y*in2, u2.z*in2};
    float s = f3dot(f3cross(v0, n1), n2);
    float sgn = (s > 0.f) ? 1.f : ((s < 0.f) ? -1.f : 0.f);
    float c = f3dot(n1, n2);
    c = fminf(fmaxf(c, -1.f + 1e-7f), 1.f - 1e-7f);
    return sgn * acosf(c);
}

// ---------------- weight split+pack prep kernel (proven layout) ----------------
__global__ __launch_bounds__(256)
void prep_w(const float* __restrict__ w1, const float* __restrict__ w2,
            const float* __restrict__ w3, const float* __restrict__ w4,
            const float* __restrict__ w5, u16* __restrict__ ws)
{
    int idx = blockIdx.x * 256 + threadIdx.x;
    if (idx >= WS_TOTAL) return;
    const float* W; int Kreal, rel; bool lo = false;
    if      (idx < WS_B2)   { W = w1; Kreal = 225; rel = idx; }
    else if (idx < WS_B3)   { W = w2; Kreal = 128; rel = idx - WS_B2; }
    else if (idx < WS_B4)   { W = w3; Kreal = 410; rel = idx - WS_B3; }
    else if (idx < WS_B5)   { W = w4; Kreal = 128; rel = idx - WS_B4; }
    else if (idx < WS_L4LO) { W = w5; Kreal = 128; rel = idx - WS_B5; }
    else if (idx < WS_L5LO) { W = w4; Kreal = 128; rel = idx - WS_L4LO; lo = true; }
    else                    { W = w5; Kreal = 128; rel = idx - WS_L5LO; lo = true; }
    int e = rel & 7, lane = (rel >> 3) & 63, ct = (rel >> 9) & 7, kt = rel >> 12;
    int k = kt*32 + ((lane >> 4) << 3) + e;
    int col = ct*16 + (lane & 15);
    float v = (k < Kreal) ? W[k*128 + col] : 0.f;
    u16 h = f2bf(v);
    ws[idx] = lo ? f2bf(v - bf2f(h)) : h;
}

// softplus(distcoef) table: 484 aa-pairs x 225 atom-pairs, f32
__global__ __launch_bounds__(256)
void prep_sp(const float* __restrict__ dc, float* __restrict__ sp)
{
    int i = blockIdx.x * 256 + threadIdx.x;
    if (i < SP_N){
        float cw = dc[i];
        sp[i] = fmaxf(cw, 0.f) + log1pf(expf(-fabsf(cw)));
    }
}

// ---------------- dual-group single-ct MFMA gemm ----------------
// Proven gemm16 addressing on two independent A buffers sharing one B stream.
template<int T>
__device__ inline void gemm16d(const u16* __restrict__ A0, const u16* __restrict__ A1,
                               int lda, const u16* __restrict__ B,
                               int ct, int lane, f32x4 acc[2])
{
    const int r15 = lane & 15;
    const int koff = (lane >> 4) << 3;
    const int sx = (r15 & 7) << 3;
    const u16* a0p = A0 + r15*lda;
    const u16* a1p = A1 + r15*lda;
#pragma unroll
    for (int kt = 0; kt < T; ++kt){
        int kk = ((kt << 5) + koff) ^ sx;
        bf16x8 a0 = *(const bf16x8*)(a0p + kk);
        bf16x8 a1 = *(const bf16x8*)(a1p + kk);
        bf16x8 b  = *(const bf16x8*)(B + (((kt*8 + ct)*64 + lane) << 3));
        acc[0] = MFMA(a0, b, acc[0], 0, 0, 0);
        acc[1] = MFMA(a1, b, acc[1], 0, 0, 0);
    }
}

// split variant: per group acc += Ahi*Bhi + Ahi*Blo + Alo*Bhi
template<int T>
__device__ inline void gemm16ds(const u16* __restrict__ Ah0, const u16* __restrict__ Al0,
                                const u16* __restrict__ Ah1, const u16* __restrict__ Al1,
                                int lda, const u16* __restrict__ Bh, const u16* __restrict__ Bl,
                                int ct, int lane, f32x4 acc[2])
{
    const int r15 = lane & 15;
    const int koff = (lane >> 4) << 3;
    const int sx = (r15 & 7) << 3;
#pragma unroll
    for (int kt = 0; kt < T; ++kt){
        int kk = ((kt << 5) + koff) ^ sx;
        bf16x8 ah0 = *(const bf16x8*)(Ah0 + r15*lda + kk);
        bf16x8 al0 = *(const bf16x8*)(Al0 + r15*lda + kk);
        bf16x8 ah1 = *(const bf16x8*)(Ah1 + r15*lda + kk);
        bf16x8 al1 = *(const bf16x8*)(Al1 + r15*lda + kk);
        const int bo = ((kt*8 + ct)*64 + lane) << 3;
        bf16x8 bh = *(const bf16x8*)(Bh + bo);
        bf16x8 bl = *(const bf16x8*)(Bl + bo);
        acc[0] = MFMA(ah0, bh, acc[0], 0, 0, 0);
        acc[0] = MFMA(ah0, bl, acc[0], 0, 0, 0);
        acc[0] = MFMA(al0, bh, acc[0], 0, 0, 0);
        acc[1] = MFMA(ah1, bh, acc[1], 0, 0, 0);
        acc[1] = MFMA(ah1, bl, acc[1], 0, 0, 0);
        acc[1] = MFMA(al1, bh, acc[1], 0, 0, 0);
    }
}

// epilogue, single-ct dual-group: bias+relu -> swizzled bf16 LDS (proven C/D mapping)
__device__ inline void epi16d(f32x4 acc[2], const float* __restrict__ bias,
                              int ct, int lane,
                              u16* D0hi, u16* D0lo, u16* D1hi, u16* D1lo)
{
    const int rr = (lane >> 4) << 2;
    const int col = ct*16 + (lane & 15);
    const float b = bias[col];
#pragma unroll
    for (int r = 0; r < 4; ++r){
        int m = rr + r;
        int idx = m*128 + (col ^ ((m & 7) << 3));
        float v0 = fmaxf(acc[0][r] + b, 0.f);
        float v1 = fmaxf(acc[1][r] + b, 0.f);
        u16 h0 = f2bf(v0), h1 = f2bf(v1);
        D0hi[idx] = h0;
        D1hi[idx] = h1;
        if (D0lo) D0lo[idx] = f2bf(v0 - bf2f(h0));
        if (D1lo) D1lo[idx] = f2bf(v1 - bf2f(h1));
    }
}

// ---------------- main fused kernel: 512 threads, 2 groups, B shared across groups ----------------
__global__ __launch_bounds__(512, 6)
void rpe_mfma5(const int* __restrict__ aa, const int* __restrict__ res_nb,
               const int* __restrict__ chain_nb,
               const float* __restrict__ pos_atoms, const float* __restrict__ mask_atoms,
               const float* __restrict__ aa_embed_w, const float* __restrict__ relpos_embed_w,
               const float* __restrict__ sp_table,
               const float* __restrict__ dist_b1, const float* __restrict__ dist_b2,
               const float* __restrict__ out_b1, const float* __restrict__ out_b2,
               const float* __restrict__ out_b3,
               const u16* __restrict__ ws, float* __restrict__ out)
{
    const int t  = threadIdx.x;
    const int g  = t >> 8;          // feature-phase group 0/1
    const int tl = t & 255;
    const int bid = blockIdx.x;     // 0..4095
    const int n  = bid >> 11;
    const int i  = (bid >> 3) & 255;
    const int j0b = (bid & 7) << 5; // block j-base (32 pairs)
    const int j0 = j0b + g*16;      // this group's j-base
    const int ri = n*L_SEQ + i;
    const int rj0 = n*L_SEQ + j0;

    __shared__ __align__(16) u16 s_g[2][TMP*256];    // gauss | L3+: h3h @0, h3l @2048
    __shared__ __align__(16) u16 s_c1[2][TMP*256];   // aapair|relpos | L4+: h4h @0, h4l @2048
    __shared__ __align__(16) u16 s_c2[2][TMP*128];   // dist feat
    __shared__ __align__(16) u16 s_c3[2][TMP*64];    // dihed (26+pad)
    __shared__ __align__(16) u16 s_h1s[2][TMP*128];  // h1; ALIASED with f32 staging (dead by L1-epi)
    __shared__ int   s_aap[2][TMP];
    __shared__ int   s_rp[2][TMP];
    __shared__ float s_same[2][TMP];
    __shared__ float s_mpair[2][TMP];

    float* stage   = (float*)s_h1s[g];
    float* u_posj  = stage;              // 720
    float* u_posi  = stage + 720;        // 45
    float* u_maskj = stage + 768;        // 240
    float* u_maski = stage + 1008;       // 15

    // ---- stage residue data (per group) ----
    for (int idx = tl; idx < TMP*45; idx += 256) u_posj[idx] = pos_atoms[rj0*45 + idx];
    if (tl < 45) u_posi[tl] = pos_atoms[ri*45 + tl];
    for (int idx = tl; idx < TMP*15; idx += 256) u_maskj[idx] = mask_atoms[rj0*15 + idx];
    if (tl >= 64 && tl < 79) u_maski[tl - 64] = mask_atoms[ri*15 + (tl - 64)];
    if (tl >= 96 && tl < 96 + TMP){
        int m = tl - 96, rj = rj0 + m;
        s_aap[g][m] = aa[ri]*22 + aa[rj];
        int d = res_nb[ri] - res_nb[rj];
        d = min(max(d, -32), 32);
        s_rp[g][m] = d + 32;
        s_same[g][m] = (chain_nb[ri] == chain_nb[rj]) ? 1.f : 0.f;
    }
    __syncthreads();   // B1: staging complete

    if (tl < TMP) s_mpair[g][tl] = u_maski[1] * u_maskj[tl*15 + 1];   // BB_CA = 1

    // ---- gaussian distance features: k = tl fixed per thread, loop over m ----
    {
        const int kg = tl;
        const bool act = kg < 225;
        int ga = 0, gb = 0;
        float pix = 0, piy = 0, piz = 0, mi_a = 0;
        if (act){
            ga = kg / 15; gb = kg - ga*15;
            pix = u_posi[ga*3+0]; piy = u_posi[ga*3+1]; piz = u_posi[ga*3+2];
            mi_a = u_maski[ga];
        }
#pragma unroll 4
        for (int m = 0; m < TMP; ++m){
            float gv = 0.f;
            if (act){
                float dx = pix - u_posj[m*45 + gb*3+0];
                float dy = piy - u_posj[m*45 + gb*3+1];
                float dz = piz - u_posj[m*45 + gb*3+2];
                float d2 = (dx*dx + dy*dy + dz*dz + 1e-10f) * 0.01f;
                float c = sp_table[s_aap[g][m]*225 + kg];
                gv = expf(-c*d2) * mi_a * u_maskj[m*15 + gb];
            }
            s_g[g][swz(m, kg, 256)] = f2bf(gv);
        }
    }

    // ---- embedding gathers (bf16, swizzled) ----
    {
        const int c = tl & 127;
        const int mb = tl >> 7;
#pragma unroll
        for (int it = 0; it < 8; ++it){
            int m = mb + it*2;
            s_c1[g][swz(m, c,       256)] = f2bf(aa_embed_w[s_aap[g][m]*128 + c]);
            s_c1[g][swz(m, 128 + c, 256)] = f2bf(s_same[g][m] * relpos_embed_w[s_rp[g][m]*128 + c]);
        }
    }

    // ---- dihedral features (bf16 into s_c3) ----
    if (tl < 2*TMP){
        int m = tl >> 1, w = tl & 1;
        F3 P0, P1, P2, P3;
        if (w == 0){   // phi: pC_i, pN_j, pCA_j, pC_j
            P0 = {u_posi[6],  u_posi[7],  u_posi[8]};
            P1 = {u_posj[m*45+0], u_posj[m*45+1], u_posj[m*45+2]};
            P2 = {u_posj[m*45+3], u_posj[m*45+4], u_posj[m*45+5]};
            P3 = {u_posj[m*45+6], u_posj[m*45+7], u_posj[m*45+8]};
        } else {       // psi: pN_i, pCA_i, pC_i, pN_j
            P0 = {u_posi[0], u_posi[1], u_posi[2]};
            P1 = {u_posi[3], u_posi[4], u_posi[5]};
            P2 = {u_posi[6], u_posi[7], u_posi[8]};
            P3 = {u_posj[m*45+0], u_posj[m*45+1], u_posj[m*45+2]};
        }
        float x = dihedral(P0, P1, P2, P3);
        int kb = w*13;
        u16* c3 = s_c3[g];
        c3[swz(m, kb+0,  64)] = f2bf(x);
        c3[swz(m, kb+1,  64)] = f2bf(sinf(x));
        c3[swz(m, kb+2,  64)] = f2bf(sinf(2.f*x));
        c3[swz(m, kb+3,  64)] = f2bf(sinf(3.f*x));
        c3[swz(m, kb+4,  64)] = f2bf(sinf(x));
        c3[swz(m, kb+5,  64)] = f2bf(sinf(0.5f*x));
        c3[swz(m, kb+6,  64)] = f2bf(sinf(x*(1.f/3.f)));
        c3[swz(m, kb+7,  64)] = f2bf(cosf(x));
        c3[swz(m, kb+8,  64)] = f2bf(cosf(2.f*x));
        c3[swz(m, kb+9,  64)] = f2bf(cosf(3.f*x));
        c3[swz(m, kb+10, 64)] = f2bf(cosf(x));
        c3[swz(m, kb+11, 64)] = f2bf(cosf(0.5f*x));
        c3[swz(m, kb+12, 64)] = f2bf(cosf(x*(1.f/3.f)));
    }
    for (int idx = tl; idx < TMP*38; idx += 256){ int m = idx/38; s_c3[g][swz(m, 26 + idx - m*38, 64)] = 0; }
    __syncthreads();   // B2: features complete

    const int lane = t & 63;
    const int w = t >> 6;          // wave -> ONE ct index (0..7), both groups

    u16* h3h0 = s_g[0];   u16* h3l0 = s_g[0]  + 2048;
    u16* h3h1 = s_g[1];   u16* h3l1 = s_g[1]  + 2048;
    u16* h4h0 = s_c1[0];  u16* h4l0 = s_c1[0] + 2048;
    u16* h4h1 = s_c1[1];  u16* h4l1 = s_c1[1] + 2048;

    // ---- L1: h1 = relu(g @ W1 + b1) ----
    f32x4 acc[2];
    acc[0] = {0,0,0,0}; acc[1] = {0,0,0,0};
    gemm16d<8>(s_g[0], s_g[1], 256, ws + WS_B1, w, lane, acc);
    epi16d(acc, dist_b1, w, lane, s_h1s[0], nullptr, s_h1s[1], nullptr);  // overwrites dead staging
    __syncthreads();   // B3

    // ---- L2: feat_dist = relu(h1 @ W2 + b2) ----
    acc[0] = {0,0,0,0}; acc[1] = {0,0,0,0};
    gemm16d<4>(s_h1s[0], s_h1s[1], 128, ws + WS_B2, w, lane, acc);
    epi16d(acc, dist_b2, w, lane, s_c2[0], nullptr, s_c2[1], nullptr);
    __syncthreads();   // B4

    // ---- L3: h3 = relu([c1|c2|c3] @ W3 + b3) -> hi+lo (aliases s_g) ----
    acc[0] = {0,0,0,0}; acc[1] = {0,0,0,0};
    gemm16d<8>(s_c1[0], s_c1[1], 256, ws + WS_B3,           w, lane, acc);
    gemm16d<4>(s_c2[0], s_c2[1], 128, ws + WS_B3 +  8*4096, w, lane, acc);
    gemm16d<1>(s_c3[0], s_c3[1],  64, ws + WS_B3 + 12*4096, w, lane, acc);
    epi16d(acc, out_b1, w, lane, h3h0, h3l0, h3h1, h3l1);
    __syncthreads();   // B5

    // ---- L4: h4 = relu(h3 @ W4 + b4) (split; aliases s_c1) ----
    acc[0] = {0,0,0,0}; acc[1] = {0,0,0,0};
    gemm16ds<4>(h3h0, h3l0, h3h1, h3l1, 128, ws + WS_B4, ws + WS_L4LO, w, lane, acc);
    epi16d(acc, out_b2, w, lane, h4h0, h4l0, h4h1, h4l1);
    __syncthreads();   // B6

    // ---- L5: out = (h4 @ W5 + b5) * mask_pair (split) ----
    acc[0] = {0,0,0,0}; acc[1] = {0,0,0,0};
    gemm16ds<4>(h4h0, h4l0, h4h1, h4l1, 128, ws + WS_B5, ws + WS_L5LO, w, lane, acc);
    {
        const int rr = (lane >> 4) << 2;
        const int col = w*16 + (lane & 15);
        const float b = out_b3[col];
#pragma unroll
        for (int gg = 0; gg < 2; ++gg){
            int jg = j0b + gg*16;
#pragma unroll
            for (int r = 0; r < 4; ++r){
                int m = rr + r;
                out[((size_t)(ri*L_SEQ) + (size_t)(jg + m))*128 + col] = (acc[gg][r] + b) * s_mpair[gg][m];
            }
        }
    }
}

extern "C" void kernel_launch(void* const* d_in, const int* in_sizes, int n_in,
                              void* d_out, int out_size, void* d_ws, size_t ws_size,
                              hipStream_t stream) {
    const int*   aa             = (const int*)  d_in[0];
    const int*   res_nb         = (const int*)  d_in[1];
    const int*   chain_nb       = (const int*)  d_in[2];
    const float* pos_atoms      = (const float*)d_in[3];
    const float* mask_atoms     = (const float*)d_in[4];
    const float* aa_embed_w     = (const float*)d_in[5];
    const float* relpos_embed_w = (const float*)d_in[6];
    const float* distcoef_w     = (const float*)d_in[7];
    const float* dist_w1        = (const float*)d_in[8];
    const float* dist_b1        = (const float*)d_in[9];
    const float* dist_w2        = (const float*)d_in[10];
    const float* dist_b2        = (const float*)d_in[11];
    const float* out_w1         = (const float*)d_in[12];
    const float* out_b1         = (const float*)d_in[13];
    const float* out_w2         = (const float*)d_in[14];
    const float* out_b2         = (const float*)d_in[15];
    const float* out_w3         = (const float*)d_in[16];
    const float* out_b3         = (const float*)d_in[17];
    float* out = (float*)d_out;
    u16* ws = (u16*)d_ws;
    float* sp = (float*)(ws + WS_TOTAL);

    hipLaunchKernelGGL(prep_w, dim3((WS_TOTAL + 255)/256), dim3(256), 0, stream,
                       dist_w1, dist_w2, out_w1, out_w2, out_w3, ws);
    hipLaunchKernelGGL(prep_sp, dim3((SP_N + 255)/256), dim3(256), 0, stream,
                       distcoef_w, sp);

    const int nblocks = 2 * L_SEQ * (L_SEQ / 32);   // 4096
    hipLaunchKernelGGL(rpe_mfma5, dim3(nblocks), dim3(512), 0, stream,
                       aa, res_nb, chain_nb, pos_atoms, mask_atoms,
                       aa_embed_w, relpos_embed_w, sp,
                       dist_b1, dist_b2, out_b1, out_b2, out_b3,
                       ws, out);
}

// Round 9
// 108.547 us; speedup vs baseline: 10.1932x; 1.1071x over previous
//
#include <hip/hip_runtime.h>
#include <math.h>

typedef __attribute__((ext_vector_type(8))) short bf16x8;
typedef __attribute__((ext_vector_type(4))) float f32x4;
typedef unsigned short u16;

#define L_SEQ 256
#define TMP 16      // pairs per group
#define MFMA __builtin_amdgcn_mfma_f32_16x16x32_bf16

// ws element offsets (u16 elements). Packed B-fragment layout per layer:
// [kt][ct(8)][lane(64)][e(8)], elem = W[kt*32 + (lane>>4)*8 + e][ct*16 + (lane&15)]
#define WS_B1   0        // dist_w1: Kp=256 (K=225), 8 kt
#define WS_B2   32768    // dist_w2: Kp=128, 4 kt
#define WS_B3   49152    // out_w1:  Kp=416 (K=410), 13 kt
#define WS_B4   102400   // out_w2:  Kp=128
#define WS_B5   118784   // out_w3:  Kp=128
#define WS_L4LO 135168   // lo parts, out_w2
#define WS_L5LO 151552   // lo parts, out_w3
#define WS_TOTAL 167936  // u16 elements
#define SP_N    108900   // 484*225 (f32, pre-scaled softplus)
#define WS_EA   385736   // WS_TOTAL + SP_N*2 : bf16 aa_embed  484x128
#define WS_ER   447688   // WS_EA + 61952     : bf16 relpos    66x128 (row 65 = 0)
#define NE_A    61952
#define NE_R    8448

__device__ inline u16 f2bf(float f){
    unsigned u = __float_as_uint(f);
    unsigned r = (u + 0x7FFFu + ((u >> 16) & 1u)) >> 16;
    return (u16)r;
}
__device__ inline float bf2f(u16 h){ return __uint_as_float(((unsigned)h) << 16); }

struct F3 { float x, y, z; };
__device__ inline F3 f3sub(F3 a, F3 b){ return {a.x-b.x, a.y-b.y, a.z-b.z}; }
__device__ inline F3 f3cross(F3 a, F3 b){
    return {a.y*b.z - a.z*b.y, a.z*b.x - a.x*b.z, a.x*b.y - a.y*b.x};
}
__device__ inline float f3dot(F3 a, F3 b){ return a.x*b.x + a.y*b.y + a.z*b.z; }

__device__ inline float dihedral(F3 p0, F3 p1, F3 p2, F3 p3){
    F3 v0 = f3sub(p2, p1);
    F3 v1 = f3sub(p0, p1);
    F3 v2 = f3sub(p3, p2);
    F3 u1 = f3cross(v0, v1);
    F3 u2 = f3cross(v0, v2);
    float in1 = rsqrtf(f3dot(u1, u1) + 1e-10f);
    float in2 = rsqrtf(f3dot(u2, u2) + 1e-10f);
    F3 n1 = {u1.x*in1, u1.y*in1, u1.z*in1};
    F3 n2 = {u2.x*in2, u2.y*in2, u2.z*in2};
    float s = f3dot(f3cross(v0, n1), n2);
    float sgn = (s > 0.f) ? 1.f : ((s < 0.f) ? -1.f : 0.f);
    float c = f3dot(n1, n2);
    c = fminf(fmaxf(c, -1.f + 1e-7f), 1.f - 1e-7f);
    return sgn * acosf(c);
}

// ---------------- prep kernels ----------------
__global__ __launch_bounds__(256)
void prep_w(const float* __restrict__ w1, const float* __restrict__ w2,
            const float* __restrict__ w3, const float* __restrict__ w4,
            const float* __restrict__ w5, u16* __restrict__ ws)
{
    int idx = blockIdx.x * 256 + threadIdx.x;
    if (idx >= WS_TOTAL) return;
    const float* W; int Kreal, rel; bool lo = false;
    if      (idx < WS_B2)   { W = w1; Kreal = 225; rel = idx; }
    else if (idx < WS_B3)   { W = w2; Kreal = 128; rel = idx - WS_B2; }
    else if (idx < WS_B4)   { W = w3; Kreal = 410; rel = idx - WS_B3; }
    else if (idx < WS_B5)   { W = w4; Kreal = 128; rel = idx - WS_B4; }
    else if (idx < WS_L4LO) { W = w5; Kreal = 128; rel = idx - WS_B5; }
    else if (idx < WS_L5LO) { W = w4; Kreal = 128; rel = idx - WS_L4LO; lo = true; }
    else                    { W = w5; Kreal = 128; rel = idx - WS_L5LO; lo = true; }
    int e = rel & 7, lane = (rel >> 3) & 63, ct = (rel >> 9) & 7, kt = rel >> 12;
    int k = kt*32 + ((lane >> 4) << 3) + e;
    int col = ct*16 + (lane & 15);
    float v = (k < Kreal) ? W[k*128 + col] : 0.f;
    u16 h = f2bf(v);
    ws[idx] = lo ? f2bf(v - bf2f(h)) : h;
}

// softplus(distcoef)*0.01 table (f32) + bf16 embed tables
__global__ __launch_bounds__(256)
void prep_t(const float* __restrict__ dc, const float* __restrict__ aaw,
            const float* __restrict__ rpw, u16* __restrict__ ws)
{
    int i = blockIdx.x * 256 + threadIdx.x;
    float* sp = (float*)(ws + WS_TOTAL);
    if (i < SP_N){
        float cw = dc[i];
        sp[i] = (fmaxf(cw, 0.f) + log1pf(expf(-fabsf(cw)))) * 0.01f;
    }
    if (i < NE_A) ws[WS_EA + i] = f2bf(aaw[i]);
    if (i < NE_R) ws[WS_ER + i] = (i >> 7) < 65 ? f2bf(rpw[i]) : (u16)0;
}

// ---------------- dual-group single-ct MFMA gemm (proven core; SWZ selects XOR) ----------------
template<int T, bool SWZ>
__device__ inline void gemm16d(const u16* __restrict__ A0, const u16* __restrict__ A1,
                               int lda, const u16* __restrict__ B,
                               int ct, int lane, f32x4 acc[2])
{
    const int r15 = lane & 15;
    const int koff = (lane >> 4) << 3;
    const int sx = SWZ ? ((r15 & 7) << 3) : 0;
    const u16* a0p = A0 + r15*lda;
    const u16* a1p = A1 + r15*lda;
#pragma unroll
    for (int kt = 0; kt < T; ++kt){
        int kk = ((kt << 5) + koff) ^ sx;
        bf16x8 a0 = *(const bf16x8*)(a0p + kk);
        bf16x8 a1 = *(const bf16x8*)(a1p + kk);
        bf16x8 b  = *(const bf16x8*)(B + (((kt*8 + ct)*64 + lane) << 3));
        acc[0] = MFMA(a0, b, acc[0], 0, 0, 0);
        acc[1] = MFMA(a1, b, acc[1], 0, 0, 0);
    }
}

// split variant (always on XOR-swizzled h buffers): acc += Ah*Bh + Ah*Bl + Al*Bh
template<int T>
__device__ inline void gemm16ds(const u16* __restrict__ Ah0, const u16* __restrict__ Al0,
                                const u16* __restrict__ Ah1, const u16* __restrict__ Al1,
                                int lda, const u16* __restrict__ Bh, const u16* __restrict__ Bl,
                                int ct, int lane, f32x4 acc[2])
{
    const int r15 = lane & 15;
    const int koff = (lane >> 4) << 3;
    const int sx = (r15 & 7) << 3;
#pragma unroll
    for (int kt = 0; kt < T; ++kt){
        int kk = ((kt << 5) + koff) ^ sx;
        bf16x8 ah0 = *(const bf16x8*)(Ah0 + r15*lda + kk);
        bf16x8 al0 = *(const bf16x8*)(Al0 + r15*lda + kk);
        bf16x8 ah1 = *(const bf16x8*)(Ah1 + r15*lda + kk);
        bf16x8 al1 = *(const bf16x8*)(Al1 + r15*lda + kk);
        const int bo = ((kt*8 + ct)*64 + lane) << 3;
        bf16x8 bh = *(const bf16x8*)(Bh + bo);
        bf16x8 bl = *(const bf16x8*)(Bl + bo);
        acc[0] = MFMA(ah0, bh, acc[0], 0, 0, 0);
        acc[0] = MFMA(ah0, bl, acc[0], 0, 0, 0);
        acc[0] = MFMA(al0, bh, acc[0], 0, 0, 0);
        acc[1] = MFMA(ah1, bh, acc[1], 0, 0, 0);
        acc[1] = MFMA(ah1, bl, acc[1], 0, 0, 0);
        acc[1] = MFMA(al1, bh, acc[1], 0, 0, 0);
    }
}

// epilogue (proven C/D mapping, XOR-swizzled lda-128 dest)
__device__ inline void epi16d(f32x4 acc[2], const float* __restrict__ bias,
                              int ct, int lane,
                              u16* D0hi, u16* D0lo, u16* D1hi, u16* D1lo)
{
    const int rr = (lane >> 4) << 2;
    const int col = ct*16 + (lane & 15);
    const float b = bias[col];
#pragma unroll
    for (int r = 0; r < 4; ++r){
        int m = rr + r;
        int idx = m*128 + (col ^ ((m & 7) << 3));
        float v0 = fmaxf(acc[0][r] + b, 0.f);
        float v1 = fmaxf(acc[1][r] + b, 0.f);
        u16 h0 = f2bf(v0), h1 = f2bf(v1);
        D0hi[idx] = h0;
        D1hi[idx] = h1;
        if (D0lo) D0lo[idx] = f2bf(v0 - bf2f(h0));
        if (D1lo) D1lo[idx] = f2bf(v1 - bf2f(h1));
    }
}

// ---------------- main fused kernel: 512 threads, 2 groups, B shared across groups ----------------
__global__ __launch_bounds__(512, 6)
void rpe_mfma6(const int* __restrict__ aa, const int* __restrict__ res_nb,
               const int* __restrict__ chain_nb,
               const float* __restrict__ pos_atoms, const float* __restrict__ mask_atoms,
               const float* __restrict__ dist_b1, const float* __restrict__ dist_b2,
               const float* __restrict__ out_b1, const float* __restrict__ out_b2,
               const float* __restrict__ out_b3,
               const u16* __restrict__ ws, float* __restrict__ out)
{
    const int t  = threadIdx.x;
    const int g  = t >> 8;          // feature-phase group 0/1
    const int tl = t & 255;
    const int bid = blockIdx.x;     // 0..4095
    const int n  = bid >> 11;
    const int i  = (bid >> 3) & 255;
    const int j0b = (bid & 7) << 5; // block j-base (32 pairs)
    const int j0 = j0b + g*16;
    const int ri = n*L_SEQ + i;
    const int rj0 = n*L_SEQ + j0;

    // LDS ~51.5 KB -> 3 blocks/CU
    __shared__ __align__(16) u16 s_g[2][TMP*264];    // gauss, PADDED lda 264 | L3+: h3h @0, h3l @2048 (lda128 swz)
    __shared__ __align__(16) u16 s_c1[2][TMP*264];   // aapair|relpos, PADDED | L4+: h4h @0, h4l @2048
    __shared__ __align__(16) u16 s_c2[2][TMP*128];   // dist feat (XOR swz)
    __shared__ __align__(16) u16 s_c3[2][TMP*32];    // dihed, plain lda 32 (26 + pad)
    __shared__ __align__(16) u16 s_h1s[2][TMP*128];  // h1 (XOR swz); ALIASED with f32 staging
    __shared__ int   s_aapE[2][TMP];   // aap*256  (byte row offset, bf16 aa table)
    __shared__ int   s_aapS[2][TMP];   // aap*225  (f32 element row offset, sp table)
    __shared__ int   s_rpE[2][TMP];    // (same? rp:65)*256 byte row offset
    __shared__ float s_mpair[2][TMP];

    const float* sp_table = (const float*)(ws + WS_TOTAL);

    float* stage   = (float*)s_h1s[g];
    float* u_posj  = stage;              // 720
    float* u_posi  = stage + 720;        // 45
    float* u_maskj = stage + 768;        // 240
    float* u_maski = stage + 1008;       // 15

    // ---- stage residue data (per group) ----
    for (int idx = tl; idx < TMP*45; idx += 256) u_posj[idx] = pos_atoms[rj0*45 + idx];
    if (tl < 45) u_posi[tl] = pos_atoms[ri*45 + tl];
    for (int idx = tl; idx < TMP*15; idx += 256) u_maskj[idx] = mask_atoms[rj0*15 + idx];
    if (tl >= 64 && tl < 79) u_maski[tl - 64] = mask_atoms[ri*15 + (tl - 64)];
    if (tl >= 96 && tl < 96 + TMP){
        int m = tl - 96, rj = rj0 + m;
        int aap = aa[ri]*22 + aa[rj];
        s_aapE[g][m] = aap << 8;        // *256 B
        s_aapS[g][m] = aap * 225;       // f32 elements
        int d = res_nb[ri] - res_nb[rj];
        d = min(max(d, -32), 32);
        bool same = (chain_nb[ri] == chain_nb[rj]);
        s_rpE[g][m] = (same ? (d + 32) : 65) << 8;
    }
    __syncthreads();   // B1: staging complete

    if (tl < TMP) s_mpair[g][tl] = u_maski[1] * u_maskj[tl*15 + 1];   // BB_CA = 1

    // ---- gaussian distance features: k = tl fixed per thread, loop over m (plain padded store) ----
    {
        const int kg = tl;
        const bool act = kg < 225;
        if (act){
            int ga = kg / 15, gb = kg - ga*15;
            float pix = u_posi[ga*3+0], piy = u_posi[ga*3+1], piz = u_posi[ga*3+2];
            float mi_a = u_maski[ga];
#pragma unroll
            for (int m = 0; m < TMP; ++m){
                float dx = pix - u_posj[m*45 + gb*3+0];
                float dy = piy - u_posj[m*45 + gb*3+1];
                float dz = piz - u_posj[m*45 + gb*3+2];
                float d2 = fmaf(dz, dz, fmaf(dy, dy, fmaf(dx, dx, 1e-10f)));
                float c  = sp_table[s_aapS[g][m] + kg];          // already *0.01
                float gv = expf(-c*d2) * (mi_a * u_maskj[m*15 + gb]);
                s_g[g][m*264 + kg] = f2bf(gv);
            }
        } else {
#pragma unroll
            for (int m = 0; m < TMP; ++m) s_g[g][m*264 + kg] = 0;   // zero cols 225..255
        }
    }

    // ---- embedding gathers: pure 16B copies from pre-converted bf16 tables ----
    {
        const u16* EA = ws + WS_EA;
        const u16* ER = ws + WS_ER;
#pragma unroll
        for (int it = 0; it < 2; ++it){
            int cid = tl + it*256;            // 0..511
            int m = cid >> 5, ch = cid & 31;  // 32 chunks of 8 u16 per row
            const u16* src = (ch < 16)
                ? (const u16*)((const char*)EA + s_aapE[g][m] + (ch << 4))
                : (const u16*)((const char*)ER + s_rpE[g][m] + ((ch - 16) << 4));
            *(bf16x8*)(s_c1[g] + m*264 + (ch << 3)) = *(const bf16x8*)src;
        }
    }

    // ---- dihedral features (plain lda-32 store) ----
    if (tl < 2*TMP){
        int m = tl >> 1, w = tl & 1;
        F3 P0, P1, P2, P3;
        if (w == 0){   // phi: pC_i, pN_j, pCA_j, pC_j
            P0 = {u_posi[6],  u_posi[7],  u_posi[8]};
            P1 = {u_posj[m*45+0], u_posj[m*45+1], u_posj[m*45+2]};
            P2 = {u_posj[m*45+3], u_posj[m*45+4], u_posj[m*45+5]};
            P3 = {u_posj[m*45+6], u_posj[m*45+7], u_posj[m*45+8]};
        } else {       // psi: pN_i, pCA_i, pC_i, pN_j
            P0 = {u_posi[0], u_posi[1], u_posi[2]};
            P1 = {u_posi[3], u_posi[4], u_posi[5]};
            P2 = {u_posi[6], u_posi[7], u_posi[8]};
            P3 = {u_posj[m*45+0], u_posj[m*45+1], u_posj[m*45+2]};
        }
        float x = dihedral(P0, P1, P2, P3);
        u16* c3 = s_c3[g] + m*32 + w*13;
        c3[0]  = f2bf(x);
        c3[1]  = f2bf(sinf(x));
        c3[2]  = f2bf(sinf(2.f*x));
        c3[3]  = f2bf(sinf(3.f*x));
        c3[4]  = f2bf(sinf(x));
        c3[5]  = f2bf(sinf(0.5f*x));
        c3[6]  = f2bf(sinf(x*(1.f/3.f)));
        c3[7]  = f2bf(cosf(x));
        c3[8]  = f2bf(cosf(2.f*x));
        c3[9]  = f2bf(cosf(3.f*x));
        c3[10] = f2bf(cosf(x));
        c3[11] = f2bf(cosf(0.5f*x));
        c3[12] = f2bf(cosf(x*(1.f/3.f)));
    }
    if (tl < TMP*6){ int m = tl/6; s_c3[g][m*32 + 26 + tl - m*6] = 0; }   // pad cols 26..31
    __syncthreads();   // B2: features complete

    const int lane = t & 63;
    const int w = t >> 6;          // wave -> ONE ct index (0..7), both groups

    u16* h3h0 = s_g[0];   u16* h3l0 = s_g[0]  + 2048;
    u16* h3h1 = s_g[1];   u16* h3l1 = s_g[1]  + 2048;
    u16* h4h0 = s_c1[0];  u16* h4l0 = s_c1[0] + 2048;
    u16* h4h1 = s_c1[1];  u16* h4l1 = s_c1[1] + 2048;

    // ---- L1: h1 = relu(g @ W1 + b1) ----
    f32x4 acc[2];
    acc[0] = {0,0,0,0}; acc[1] = {0,0,0,0};
    gemm16d<8,false>(s_g[0], s_g[1], 264, ws + WS_B1, w, lane, acc);
    epi16d(acc, dist_b1, w, lane, s_h1s[0], nullptr, s_h1s[1], nullptr);  // overwrites dead staging
    __syncthreads();   // B3

    // ---- L2: feat_dist = relu(h1 @ W2 + b2) ----
    acc[0] = {0,0,0,0}; acc[1] = {0,0,0,0};
    gemm16d<4,true>(s_h1s[0], s_h1s[1], 128, ws + WS_B2, w, lane, acc);
    epi16d(acc, dist_b2, w, lane, s_c2[0], nullptr, s_c2[1], nullptr);
    __syncthreads();   // B4

    // ---- L3: h3 = relu([c1|c2|c3] @ W3 + b3) -> hi+lo (aliases s_g) ----
    acc[0] = {0,0,0,0}; acc[1] = {0,0,0,0};
    gemm16d<8,false>(s_c1[0], s_c1[1], 264, ws + WS_B3,           w, lane, acc);
    gemm16d<4,true >(s_c2[0], s_c2[1], 128, ws + WS_B3 +  8*4096, w, lane, acc);
    gemm16d<1,false>(s_c3[0], s_c3[1],  32, ws + WS_B3 + 12*4096, w, lane, acc);
    epi16d(acc, out_b1, w, lane, h3h0, h3l0, h3h1, h3l1);
    __syncthreads();   // B5

    // ---- L4: h4 = relu(h3 @ W4 + b4) (split; aliases s_c1) ----
    acc[0] = {0,0,0,0}; acc[1] = {0,0,0,0};
    gemm16ds<4>(h3h0, h3l0, h3h1, h3l1, 128, ws + WS_B4, ws + WS_L4LO, w, lane, acc);
    epi16d(acc, out_b2, w, lane, h4h0, h4l0, h4h1, h4l1);
    __syncthreads();   // B6

    // ---- L5: out = (h4 @ W5 + b5) * mask_pair (split) ----
    acc[0] = {0,0,0,0}; acc[1] = {0,0,0,0};
    gemm16ds<4>(h4h0, h4l0, h4h1, h4l1, 128, ws + WS_B5, ws + WS_L5LO, w, lane, acc);
    {
        const int rr = (lane >> 4) << 2;
        const int col = w*16 + (lane & 15);
        const float b = out_b3[col];
#pragma unroll
        for (int gg = 0; gg < 2; ++gg){
            int jg = j0b + gg*16;
#pragma unroll
            for (int r = 0; r < 4; ++r){
                int m = rr + r;
                out[((size_t)(ri*L_SEQ) + (size_t)(jg + m))*128 + col] = (acc[gg][r] + b) * s_mpair[gg][m];
            }
        }
    }
}

extern "C" void kernel_launch(void* const* d_in, const int* in_sizes, int n_in,
                              void* d_out, int out_size, void* d_ws, size_t ws_size,
                              hipStream_t stream) {
    const int*   aa             = (const int*)  d_in[0];
    const int*   res_nb         = (const int*)  d_in[1];
    const int*   chain_nb       = (const int*)  d_in[2];
    const float* pos_atoms      = (const float*)d_in[3];
    const float* mask_atoms     = (const float*)d_in[4];
    const float* aa_embed_w     = (const float*)d_in[5];
    const float* relpos_embed_w = (const float*)d_in[6];
    const float* distcoef_w     = (const float*)d_in[7];
    const float* dist_w1        = (const float*)d_in[8];
    const float* dist_b1        = (const float*)d_in[9];
    const float* dist_w2        = (const float*)d_in[10];
    const float* dist_b2        = (const float*)d_in[11];
    const float* out_w1         = (const float*)d_in[12];
    const float* out_b1         = (const float*)d_in[13];
    const float* out_w2         = (const float*)d_in[14];
    const float* out_b2         = (const float*)d_in[15];
    const float* out_w3         = (const float*)d_in[16];
    const float* out_b3         = (const float*)d_in[17];
    float* out = (float*)d_out;
    u16* ws = (u16*)d_ws;

    hipLaunchKernelGGL(prep_w, dim3((WS_TOTAL + 255)/256), dim3(256), 0, stream,
                       dist_w1, dist_w2, out_w1, out_w2, out_w3, ws);
    hipLaunchKernelGGL(prep_t, dim3((SP_N + 255)/256), dim3(256), 0, stream,
                       distcoef_w, aa_embed_w, relpos_embed_w, ws);

    const int nblocks = 2 * L_SEQ * (L_SEQ / 32);   // 4096
    hipLaunchKernelGGL(rpe_mfma6, dim3(nblocks), dim3(512), 0, stream,
                       aa, res_nb, chain_nb, pos_atoms, mask_atoms,
                       dist_b1, dist_b2, out_b1, out_b2, out_b3,
                       ws, out);
}

// Round 10
// 104.436 us; speedup vs baseline: 10.5945x; 1.0394x over previous
//
#include <hip/hip_runtime.h>
#include <hip/hip_bf16.h>
#include <math.h>

typedef __attribute__((ext_vector_type(8))) short bf16x8;
typedef __attribute__((ext_vector_type(4))) float f32x4;
typedef unsigned short u16;

#define L_SEQ 256
#define TMP 16      // pairs per group
#define MFMA __builtin_amdgcn_mfma_f32_16x16x32_bf16

// ws element offsets (u16 elements). Packed B-fragment layout per layer:
// [kt][ct(8)][lane(64)][e(8)], elem = W[kt*32 + (lane>>4)*8 + e][ct*16 + (lane&15)]
#define WS_B1   0        // dist_w1: Kp=256 (K=225), 8 kt
#define WS_B2   32768    // dist_w2: Kp=128, 4 kt
#define WS_B3   49152    // out_w1:  Kp=416 (K=410), 13 kt
#define WS_B4   102400   // out_w2:  Kp=128
#define WS_B5   118784   // out_w3:  Kp=128
#define WS_L4LO 135168   // lo parts, out_w2
#define WS_L5LO 151552   // lo parts, out_w3
#define WS_TOTAL 167936  // u16 elements
#define SP_N    108900   // 484*225 (f32, pre-scaled softplus)
#define WS_EA   385736   // WS_TOTAL + SP_N*2 : bf16 aa_embed  484x128
#define WS_ER   447688   // WS_EA + 61952     : bf16 relpos    66x128 (row 65 = 0)
#define NE_A    61952
#define NE_R    8448

// manual RNE (prep kernels only)
__device__ inline u16 f2bf(float f){
    unsigned u = __float_as_uint(f);
    unsigned r = (u + 0x7FFFu + ((u >> 16) & 1u)) >> 16;
    return (u16)r;
}
// HW RNE via builtin cast (hot kernel; bit-identical to f2bf for non-NaN)
__device__ inline u16 f2bfq(float f){
    union { __hip_bfloat16 h; u16 u; } c;
    c.h = __float2bfloat16(f);
    return c.u;
}
__device__ inline float bf2f(u16 h){ return __uint_as_float(((unsigned)h) << 16); }
__device__ inline int swz(int m, int k, int lda){ return m*lda + (k ^ ((m & 7) << 3)); }

struct F3 { float x, y, z; };
__device__ inline F3 f3sub(F3 a, F3 b){ return {a.x-b.x, a.y-b.y, a.z-b.z}; }
__device__ inline F3 f3cross(F3 a, F3 b){
    return {a.y*b.z - a.z*b.y, a.z*b.x - a.x*b.z, a.x*b.y - a.y*b.x};
}
__device__ inline float f3dot(F3 a, F3 b){ return a.x*b.x + a.y*b.y + a.z*b.z; }

__device__ inline float dihedral(F3 p0, F3 p1, F3 p2, F3 p3){
    F3 v0 = f3sub(p2, p1);
    F3 v1 = f3sub(p0, p1);
    F3 v2 = f3sub(p3, p2);
    F3 u1 = f3cross(v0, v1);
    F3 u2 = f3cross(v0, v2);
    float in1 = rsqrtf(f3dot(u1, u1) + 1e-10f);
    float in2 = rsqrtf(f3dot(u2, u2) + 1e-10f);
    F3 n1 = {u1.x*in1, u1.y*in1, u1.z*in1};
    F3 n2 = {u2.x*in2, u2.y*in2, u2.z*in2};
    float s = f3dot(f3cross(v0, n1), n2);
    float sgn = (s > 0.f) ? 1.f : ((s < 0.f) ? -1.f : 0.f);
    float c = f3dot(n1, n2);
    c = fminf(fmaxf(c, -1.f + 1e-7f), 1.f - 1e-7f);
    return sgn * acosf(c);
}

// ---------------- prep kernels (unchanged) ----------------
__global__ __launch_bounds__(256)
void prep_w(const float* __restrict__ w1, const float* __restrict__ w2,
            const float* __restrict__ w3, const float* __restrict__ w4,
            const float* __restrict__ w5, u16* __restrict__ ws)
{
    int idx = blockIdx.x * 256 + threadIdx.x;
    if (idx >= WS_TOTAL) return;
    const float* W; int Kreal, rel; bool lo = false;
    if      (idx < WS_B2)   { W = w1; Kreal = 225; rel = idx; }
    else if (idx < WS_B3)   { W = w2; Kreal = 128; rel = idx - WS_B2; }
    else if (idx < WS_B4)   { W = w3; Kreal = 410; rel = idx - WS_B3; }
    else if (idx < WS_B5)   { W = w4; Kreal = 128; rel = idx - WS_B4; }
    else if (idx < WS_L4LO) { W = w5; Kreal = 128; rel = idx - WS_B5; }
    else if (idx < WS_L5LO) { W = w4; Kreal = 128; rel = idx - WS_L4LO; lo = true; }
    else                    { W = w5; Kreal = 128; rel = idx - WS_L5LO; lo = true; }
    int e = rel & 7, lane = (rel >> 3) & 63, ct = (rel >> 9) & 7, kt = rel >> 12;
    int k = kt*32 + ((lane >> 4) << 3) + e;
    int col = ct*16 + (lane & 15);
    float v = (k < Kreal) ? W[k*128 + col] : 0.f;
    u16 h = f2bf(v);
    ws[idx] = lo ? f2bf(v - bf2f(h)) : h;
}

__global__ __launch_bounds__(256)
void prep_t(const float* __restrict__ dc, const float* __restrict__ aaw,
            const float* __restrict__ rpw, u16* __restrict__ ws)
{
    int i = blockIdx.x * 256 + threadIdx.x;
    float* sp = (float*)(ws + WS_TOTAL);
    if (i < SP_N){
        float cw = dc[i];
        sp[i] = (fmaxf(cw, 0.f) + log1pf(expf(-fabsf(cw)))) * 0.01f;
    }
    if (i < NE_A) ws[WS_EA + i] = f2bf(aaw[i]);
    if (i < NE_R) ws[WS_ER + i] = (i >> 7) < 65 ? f2bf(rpw[i]) : (u16)0;
}

// ---------------- dual-group single-ct MFMA gemm (R8/R9-proven, unchanged) ----------------
template<int T, bool SWZ>
__device__ inline void gemm16d(const u16* __restrict__ A0, const u16* __restrict__ A1,
                               int lda, const u16* __restrict__ B,
                               int ct, int lane, f32x4 acc[2])
{
    const int r15 = lane & 15;
    const int koff = (lane >> 4) << 3;
    const int sx = SWZ ? ((r15 & 7) << 3) : 0;
    const u16* a0p = A0 + r15*lda;
    const u16* a1p = A1 + r15*lda;
#pragma unroll
    for (int kt = 0; kt < T; ++kt){
        int kk = ((kt << 5) + koff) ^ sx;
        bf16x8 a0 = *(const bf16x8*)(a0p + kk);
        bf16x8 a1 = *(const bf16x8*)(a1p + kk);
        bf16x8 b  = *(const bf16x8*)(B + (((kt*8 + ct)*64 + lane) << 3));
        acc[0] = MFMA(a0, b, acc[0], 0, 0, 0);
        acc[1] = MFMA(a1, b, acc[1], 0, 0, 0);
    }
}

template<int T>
__device__ inline void gemm16ds(const u16* __restrict__ Ah0, const u16* __restrict__ Al0,
                                const u16* __restrict__ Ah1, const u16* __restrict__ Al1,
                                int lda, const u16* __restrict__ Bh, const u16* __restrict__ Bl,
                                int ct, int lane, f32x4 acc[2])
{
    const int r15 = lane & 15;
    const int koff = (lane >> 4) << 3;
    const int sx = (r15 & 7) << 3;
#pragma unroll
    for (int kt = 0; kt < T; ++kt){
        int kk = ((kt << 5) + koff) ^ sx;
        bf16x8 ah0 = *(const bf16x8*)(Ah0 + r15*lda + kk);
        bf16x8 al0 = *(const bf16x8*)(Al0 + r15*lda + kk);
        bf16x8 ah1 = *(const bf16x8*)(Ah1 + r15*lda + kk);
        bf16x8 al1 = *(const bf16x8*)(Al1 + r15*lda + kk);
        const int bo = ((kt*8 + ct)*64 + lane) << 3;
        bf16x8 bh = *(const bf16x8*)(Bh + bo);
        bf16x8 bl = *(const bf16x8*)(Bl + bo);
        acc[0] = MFMA(ah0, bh, acc[0], 0, 0, 0);
        acc[0] = MFMA(ah0, bl, acc[0], 0, 0, 0);
        acc[0] = MFMA(al0, bh, acc[0], 0, 0, 0);
        acc[1] = MFMA(ah1, bh, acc[1], 0, 0, 0);
        acc[1] = MFMA(ah1, bl, acc[1], 0, 0, 0);
        acc[1] = MFMA(al1, bh, acc[1], 0, 0, 0);
    }
}

// epilogue (proven C/D mapping; converts via HW cvt)
__device__ inline void epi16d(f32x4 acc[2], const float* __restrict__ bias,
                              int ct, int lane,
                              u16* D0hi, u16* D0lo, u16* D1hi, u16* D1lo)
{
    const int rr = (lane >> 4) << 2;
    const int col = ct*16 + (lane & 15);
    const float b = bias[col];
#pragma unroll
    for (int r = 0; r < 4; ++r){
        int m = rr + r;
        int idx = m*128 + (col ^ ((m & 7) << 3));
        float v0 = fmaxf(acc[0][r] + b, 0.f);
        float v1 = fmaxf(acc[1][r] + b, 0.f);
        u16 h0 = f2bfq(v0), h1 = f2bfq(v1);
        D0hi[idx] = h0;
        D1hi[idx] = h1;
        if (D0lo) D0lo[idx] = f2bfq(v0 - bf2f(h0));
        if (D1lo) D1lo[idx] = f2bfq(v1 - bf2f(h1));
    }
}

// ---------------- main fused kernel ----------------
__global__ __launch_bounds__(512, 6)
void rpe_mfma7(const int* __restrict__ aa, const int* __restrict__ res_nb,
               const int* __restrict__ chain_nb,
               const float* __restrict__ pos_atoms, const float* __restrict__ mask_atoms,
               const float* __restrict__ dist_b1, const float* __restrict__ dist_b2,
               const float* __restrict__ out_b1, const float* __restrict__ out_b2,
               const float* __restrict__ out_b3,
               const u16* __restrict__ ws, float* __restrict__ out)
{
    const int t  = threadIdx.x;
    const int g  = t >> 8;          // feature-phase group 0/1
    const int tl = t & 255;
    const int bid = blockIdx.x;     // 0..4095
    const int n  = bid >> 11;
    const int i  = (bid >> 3) & 255;
    const int j0b = (bid & 7) << 5; // block j-base (32 pairs)
    const int j0 = j0b + g*16;
    const int ri = n*L_SEQ + i;
    const int rj0 = n*L_SEQ + j0;

    __shared__ __align__(16) u16 s_g[2][TMP*264];    // gauss, lda 264 | L3+: h3h @0, h3l @2048 (lda128 swz)
    __shared__ __align__(16) u16 s_c1[2][TMP*264];   // aapair|relpos | L4+: h4h @0, h4l @2048
    __shared__ __align__(16) u16 s_c2[2][TMP*128];   // dist feat (XOR swz)
    __shared__ __align__(16) u16 s_c3[2][TMP*32];    // dihed, plain lda 32 (26 + pad)
    __shared__ __align__(16) u16 s_h1s[2][TMP*128];  // h1 (XOR swz); ALIASED with float4 staging
    __shared__ int   s_aapE[2][TMP];   // aap*256  (byte row offset, bf16 aa table)
    __shared__ int   s_aapS[2][TMP];   // aap*225  (f32 element row offset, sp table)
    __shared__ int   s_rpE[2][TMP];    // (same? rp:65)*256 byte row offset
    __shared__ float s_mpair[2][TMP];

    const float* sp_table = (const float*)(ws + WS_TOTAL);

    // float4 staging in dead h1 region: [16 res][15 atoms] {x,y,z,mask} + [15] for residue i
    float4* u_pm4  = (float4*)s_h1s[g];      // 240 * 16B = 3840 B
    float4* u_pmi4 = u_pm4 + 240;            // 15  * 16B -> total 4080 <= 4096 B

    // ---- stage residue data (per group), packed float4 ----
    if (tl < 240){
        int base = rj0*45 + tl*3;            // tl = m*15 + b  ->  m*45 + b*3 = 3*tl
        u_pm4[tl] = make_float4(pos_atoms[base], pos_atoms[base+1], pos_atoms[base+2],
                                mask_atoms[rj0*15 + tl]);
    } else if (tl < 255){
        int b = tl - 240;
        int base = ri*45 + b*3;
        u_pmi4[b] = make_float4(pos_atoms[base], pos_atoms[base+1], pos_atoms[base+2],
                                mask_atoms[ri*15 + b]);
    }
    if (tl < TMP){
        int m = tl, rj = rj0 + m;
        int aap = aa[ri]*22 + aa[rj];
        s_aapE[g][m] = aap << 8;        // *256 B
        s_aapS[g][m] = aap * 225;       // f32 elements
        int d = res_nb[ri] - res_nb[rj];
        d = min(max(d, -32), 32);
        bool same = (chain_nb[ri] == chain_nb[rj]);
        s_rpE[g][m] = (same ? (d + 32) : 65) << 8;
    }
    __syncthreads();   // B1: staging complete

    if (tl < TMP) s_mpair[g][tl] = u_pmi4[1].w * u_pm4[tl*15 + 1].w;   // BB_CA = 1

    // ---- gaussian distance features: k = tl fixed per thread, one b128 read per m ----
    {
        const int kg = tl;
        const bool act = kg < 225;
        if (act){
            int ga = kg / 15, gb = kg - ga*15;
            float4 pi = u_pmi4[ga];
            const int sps = s_aapS[g][0];   // dummy init avoided; row offsets read per m
#pragma unroll 4
            for (int m = 0; m < TMP; ++m){
                float4 pj = u_pm4[m*15 + gb];
                float dx = pi.x - pj.x;
                float dy = pi.y - pj.y;
                float dz = pi.z - pj.z;
                float d2 = fmaf(dz, dz, fmaf(dy, dy, fmaf(dx, dx, 1e-10f)));
                float c  = sp_table[s_aapS[g][m] + kg];          // already *0.01
                float gv = expf(-c*d2) * (pi.w * pj.w);
                s_g[g][m*264 + kg] = f2bfq(gv);
            }
            (void)sps;
        } else {
#pragma unroll
            for (int m = 0; m < TMP; ++m) s_g[g][m*264 + kg] = 0;   // zero cols 225..255
        }
    }

    // ---- embedding gathers: pure 16B copies from pre-converted bf16 tables ----
    {
        const u16* EA = ws + WS_EA;
        const u16* ER = ws + WS_ER;
#pragma unroll
        for (int it = 0; it < 2; ++it){
            int cid = tl + it*256;            // 0..511
            int m = cid >> 5, ch = cid & 31;  // 32 chunks of 8 u16 per row
            const u16* src = (ch < 16)
                ? (const u16*)((const char*)EA + s_aapE[g][m] + (ch << 4))
                : (const u16*)((const char*)ER + s_rpE[g][m] + ((ch - 16) << 4));
            *(bf16x8*)(s_c1[g] + m*264 + (ch << 3)) = *(const bf16x8*)src;
        }
    }

    // ---- dihedral features (plain lda-32 store) ----
    if (tl < 2*TMP){
        int m = tl >> 1, w = tl & 1;
        F3 P0, P1, P2, P3;
        float4 q0, q1, q2, q3;
        if (w == 0){   // phi: pC_i, pN_j, pCA_j, pC_j
            q0 = u_pmi4[2];       q1 = u_pm4[m*15 + 0];
            q2 = u_pm4[m*15 + 1]; q3 = u_pm4[m*15 + 2];
        } else {       // psi: pN_i, pCA_i, pC_i, pN_j
            q0 = u_pmi4[0];       q1 = u_pmi4[1];
            q2 = u_pmi4[2];       q3 = u_pm4[m*15 + 0];
        }
        P0 = {q0.x, q0.y, q0.z}; P1 = {q1.x, q1.y, q1.z};
        P2 = {q2.x, q2.y, q2.z}; P3 = {q3.x, q3.y, q3.z};
        float x = dihedral(P0, P1, P2, P3);
        u16* c3 = s_c3[g] + m*32 + w*13;
        c3[0]  = f2bfq(x);
        c3[1]  = f2bfq(sinf(x));
        c3[2]  = f2bfq(sinf(2.f*x));
        c3[3]  = f2bfq(sinf(3.f*x));
        c3[4]  = f2bfq(sinf(x));
        c3[5]  = f2bfq(sinf(0.5f*x));
        c3[6]  = f2bfq(sinf(x*(1.f/3.f)));
        c3[7]  = f2bfq(cosf(x));
        c3[8]  = f2bfq(cosf(2.f*x));
        c3[9]  = f2bfq(cosf(3.f*x));
        c3[10] = f2bfq(cosf(x));
        c3[11] = f2bfq(cosf(0.5f*x));
        c3[12] = f2bfq(cosf(x*(1.f/3.f)));
    }
    if (tl < TMP*6){ int m = tl/6; s_c3[g][m*32 + 26 + tl - m*6] = 0; }   // pad cols 26..31
    __syncthreads();   // B2: features complete (incl. all staging reads)

    const int lane = t & 63;
    const int w = t >> 6;          // wave -> ONE ct index (0..7), both groups

    u16* h3h0 = s_g[0];   u16* h3l0 = s_g[0]  + 2048;
    u16* h3h1 = s_g[1];   u16* h3l1 = s_g[1]  + 2048;
    u16* h4h0 = s_c1[0];  u16* h4l0 = s_c1[0] + 2048;
    u16* h4h1 = s_c1[1];  u16* h4l1 = s_c1[1] + 2048;

    // ---- L1: h1 = relu(g @ W1 + b1) ----
    f32x4 acc[2];
    acc[0] = {0,0,0,0}; acc[1] = {0,0,0,0};
    gemm16d<8,false>(s_g[0], s_g[1], 264, ws + WS_B1, w, lane, acc);
    epi16d(acc, dist_b1, w, lane, s_h1s[0], nullptr, s_h1s[1], nullptr);  // overwrites dead staging
    __syncthreads();   // B3

    // ---- L2: feat_dist = relu(h1 @ W2 + b2) ----
    acc[0] = {0,0,0,0}; acc[1] = {0,0,0,0};
    gemm16d<4,true>(s_h1s[0], s_h1s[1], 128, ws + WS_B2, w, lane, acc);
    epi16d(acc, dist_b2, w, lane, s_c2[0], nullptr, s_c2[1], nullptr);
    __syncthreads();   // B4

    // ---- L3: h3 = relu([c1|c2|c3] @ W3 + b3) -> hi+lo (aliases s_g) ----
    acc[0] = {0,0,0,0}; acc[1] = {0,0,0,0};
    gemm16d<8,false>(s_c1[0], s_c1[1], 264, ws + WS_B3,           w, lane, acc);
    gemm16d<4,true >(s_c2[0], s_c2[1], 128, ws + WS_B3 +  8*4096, w, lane, acc);
    gemm16d<1,false>(s_c3[0], s_c3[1],  32, ws + WS_B3 + 12*4096, w, lane, acc);
    epi16d(acc, out_b1, w, lane, h3h0, h3l0, h3h1, h3l1);
    __syncthreads();   // B5

    // ---- L4: h4 = relu(h3 @ W4 + b4) (split; aliases s_c1) ----
    acc[0] = {0,0,0,0}; acc[1] = {0,0,0,0};
    gemm16ds<4>(h3h0, h3l0, h3h1, h3l1, 128, ws + WS_B4, ws + WS_L4LO, w, lane, acc);
    epi16d(acc, out_b2, w, lane, h4h0, h4l0, h4h1, h4l1);
    __syncthreads();   // B6

    // ---- L5: out = (h4 @ W5 + b5) * mask_pair (split) ----
    acc[0] = {0,0,0,0}; acc[1] = {0,0,0,0};
    gemm16ds<4>(h4h0, h4l0, h4h1, h4l1, 128, ws + WS_B5, ws + WS_L5LO, w, lane, acc);
    {
        const int rr = (lane >> 4) << 2;
        const int col = w*16 + (lane & 15);
        const float b = out_b3[col];
#pragma unroll
        for (int gg = 0; gg < 2; ++gg){
            int jg = j0b + gg*16;
#pragma unroll
            for (int r = 0; r < 4; ++r){
                int m = rr + r;
                out[((size_t)(ri*L_SEQ) + (size_t)(jg + m))*128 + col] = (acc[gg][r] + b) * s_mpair[gg][m];
            }
        }
    }
}

extern "C" void kernel_launch(void* const* d_in, const int* in_sizes, int n_in,
                              void* d_out, int out_size, void* d_ws, size_t ws_size,
                              hipStream_t stream) {
    const int*   aa             = (const int*)  d_in[0];
    const int*   res_nb         = (const int*)  d_in[1];
    const int*   chain_nb       = (const int*)  d_in[2];
    const float* pos_atoms      = (const float*)d_in[3];
    const float* mask_atoms     = (const float*)d_in[4];
    const float* aa_embed_w     = (const float*)d_in[5];
    const float* relpos_embed_w = (const float*)d_in[6];
    const float* distcoef_w     = (const float*)d_in[7];
    const float* dist_w1        = (const float*)d_in[8];
    const float* dist_b1        = (const float*)d_in[9];
    const float* dist_w2        = (const float*)d_in[10];
    const float* dist_b2        = (const float*)d_in[11];
    const float* out_w1         = (const float*)d_in[12];
    const float* out_b1         = (const float*)d_in[13];
    const float* out_w2         = (const float*)d_in[14];
    const float* out_b2         = (const float*)d_in[15];
    const float* out_w3         = (const float*)d_in[16];
    const float* out_b3         = (const float*)d_in[17];
    float* out = (float*)d_out;
    u16* ws = (u16*)d_ws;

    hipLaunchKernelGGL(prep_w, dim3((WS_TOTAL + 255)/256), dim3(256), 0, stream,
                       dist_w1, dist_w2, out_w1, out_w2, out_w3, ws);
    hipLaunchKernelGGL(prep_t, dim3((SP_N + 255)/256), dim3(256), 0, stream,
                       distcoef_w, aa_embed_w, relpos_embed_w, ws);

    const int nblocks = 2 * L_SEQ * (L_SEQ / 32);   // 4096
    hipLaunchKernelGGL(rpe_mfma7, dim3(nblocks), dim3(512), 0, stream,
                       aa, res_nb, chain_nb, pos_atoms, mask_atoms,
                       dist_b1, dist_b2, out_b1, out_b2, out_b3,
                       ws, out);
}

// Round 11
// 104.263 us; speedup vs baseline: 10.6120x; 1.0017x over previous
//
#include <hip/hip_runtime.h>
#include <hip/hip_bf16.h>
#include <math.h>

typedef __attribute__((ext_vector_type(8))) short bf16x8;
typedef __attribute__((ext_vector_type(4))) float f32x4;
typedef unsigned short u16;

#define L_SEQ 256
#define TMP 16      // pairs per group
#define MFMA __builtin_amdgcn_mfma_f32_16x16x32_bf16

// ws element offsets (u16 elements). Packed B-fragment layout per layer:
// [kt][ct(8)][lane(64)][e(8)], elem = W[kt*32 + (lane>>4)*8 + e][ct*16 + (lane&15)]
#define WS_B1   0        // dist_w1: Kp=256 (K=225), 8 kt
#define WS_B2   32768    // dist_w2: Kp=128, 4 kt
#define WS_B3   49152    // out_w1:  Kp=416 (K=410), 13 kt
#define WS_B4   102400   // out_w2:  Kp=128
#define WS_B5   118784   // out_w3:  Kp=128
#define WS_L4LO 135168   // lo parts, out_w2
#define WS_L5LO 151552   // lo parts, out_w3
#define WS_TOTAL 167936  // u16 elements
#define SP_N    108900   // 484*225 (f32, pre-scaled softplus)
#define WS_EA   385736   // WS_TOTAL + SP_N*2 : bf16 aa_embed  484x128
#define WS_ER   447688   // WS_EA + 61952     : bf16 relpos    66x128 (row 65 = 0)
#define NE_A    61952
#define NE_R    8448

// manual RNE (prep kernels only)
__device__ inline u16 f2bf(float f){
    unsigned u = __float_as_uint(f);
    unsigned r = (u + 0x7FFFu + ((u >> 16) & 1u)) >> 16;
    return (u16)r;
}
// HW RNE via builtin cast (hot kernel)
__device__ inline u16 f2bfq(float f){
    union { __hip_bfloat16 h; u16 u; } c;
    c.h = __float2bfloat16(f);
    return c.u;
}
__device__ inline float bf2f(u16 h){ return __uint_as_float(((unsigned)h) << 16); }

struct F3 { float x, y, z; };
__device__ inline F3 f3sub(F3 a, F3 b){ return {a.x-b.x, a.y-b.y, a.z-b.z}; }
__device__ inline F3 f3cross(F3 a, F3 b){
    return {a.y*b.z - a.z*b.y, a.z*b.x - a.x*b.z, a.x*b.y - a.y*b.x};
}
__device__ inline float f3dot(F3 a, F3 b){ return a.x*b.x + a.y*b.y + a.z*b.z; }

__device__ inline float dihedral(F3 p0, F3 p1, F3 p2, F3 p3){
    F3 v0 = f3sub(p2, p1);
    F3 v1 = f3sub(p0, p1);
    F3 v2 = f3sub(p3, p2);
    F3 u1 = f3cross(v0, v1);
    F3 u2 = f3cross(v0, v2);
    float in1 = rsqrtf(f3dot(u1, u1) + 1e-10f);
    float in2 = rsqrtf(f3dot(u2, u2) + 1e-10f);
    F3 n1 = {u1.x*in1, u1.y*in1, u1.z*in1};
    F3 n2 = {u2.x*in2, u2.y*in2, u2.z*in2};
    float s = f3dot(f3cross(v0, n1), n2);
    float sgn = (s > 0.f) ? 1.f : ((s < 0.f) ? -1.f : 0.f);
    float c = f3dot(n1, n2);
    c = fminf(fmaxf(c, -1.f + 1e-7f), 1.f - 1e-7f);
    return sgn * acosf(c);
}

// ---------------- prep kernels (unchanged) ----------------
__global__ __launch_bounds__(256)
void prep_w(const float* __restrict__ w1, const float* __restrict__ w2,
            const float* __restrict__ w3, const float* __restrict__ w4,
            const float* __restrict__ w5, u16* __restrict__ ws)
{
    int idx = blockIdx.x * 256 + threadIdx.x;
    if (idx >= WS_TOTAL) return;
    const float* W; int Kreal, rel; bool lo = false;
    if      (idx < WS_B2)   { W = w1; Kreal = 225; rel = idx; }
    else if (idx < WS_B3)   { W = w2; Kreal = 128; rel = idx - WS_B2; }
    else if (idx < WS_B4)   { W = w3; Kreal = 410; rel = idx - WS_B3; }
    else if (idx < WS_B5)   { W = w4; Kreal = 128; rel = idx - WS_B4; }
    else if (idx < WS_L4LO) { W = w5; Kreal = 128; rel = idx - WS_B5; }
    else if (idx < WS_L5LO) { W = w4; Kreal = 128; rel = idx - WS_L4LO; lo = true; }
    else                    { W = w5; Kreal = 128; rel = idx - WS_L5LO; lo = true; }
    int e = rel & 7, lane = (rel >> 3) & 63, ct = (rel >> 9) & 7, kt = rel >> 12;
    int k = kt*32 + ((lane >> 4) << 3) + e;
    int col = ct*16 + (lane & 15);
    float v = (k < Kreal) ? W[k*128 + col] : 0.f;
    u16 h = f2bf(v);
    ws[idx] = lo ? f2bf(v - bf2f(h)) : h;
}

__global__ __launch_bounds__(256)
void prep_t(const float* __restrict__ dc, const float* __restrict__ aaw,
            const float* __restrict__ rpw, u16* __restrict__ ws)
{
    int i = blockIdx.x * 256 + threadIdx.x;
    float* sp = (float*)(ws + WS_TOTAL);
    if (i < SP_N){
        float cw = dc[i];
        sp[i] = (fmaxf(cw, 0.f) + log1pf(expf(-fabsf(cw)))) * 0.01f;
    }
    if (i < NE_A) ws[WS_EA + i] = f2bf(aaw[i]);
    if (i < NE_R) ws[WS_ER + i] = (i >> 7) < 65 ? f2bf(rpw[i]) : (u16)0;
}

// ---------------- dual-group single-ct MFMA gemm, 4-deep pipelined loads ----------------
template<int T, bool SWZ>
__device__ inline void gemm16d(const u16* __restrict__ A0, const u16* __restrict__ A1,
                               int lda, const u16* __restrict__ B,
                               int ct, int lane, f32x4 acc[2])
{
    const int r15 = lane & 15;
    const int koff = (lane >> 4) << 3;
    const int sx = SWZ ? ((r15 & 7) << 3) : 0;
    const u16* a0p = A0 + r15*lda;
    const u16* a1p = A1 + r15*lda;
    constexpr int C = (T >= 4) ? 4 : T;
    static_assert(T % C == 0, "chunking");
#pragma unroll
    for (int b0 = 0; b0 < T; b0 += C){
        bf16x8 bf[C], a0[C], a1[C];
#pragma unroll
        for (int c = 0; c < C; ++c){
            int kt = b0 + c;
            bf[c] = *(const bf16x8*)(B + (((kt*8 + ct)*64 + lane) << 3));
        }
#pragma unroll
        for (int c = 0; c < C; ++c){
            int kk = (((b0 + c) << 5) + koff) ^ sx;
            a0[c] = *(const bf16x8*)(a0p + kk);
            a1[c] = *(const bf16x8*)(a1p + kk);
        }
#pragma unroll
        for (int c = 0; c < C; ++c){
            acc[0] = MFMA(a0[c], bf[c], acc[0], 0, 0, 0);
            acc[1] = MFMA(a1[c], bf[c], acc[1], 0, 0, 0);
        }
    }
}

// split variant, 2-deep chunks: acc += Ah*Bh + Ah*Bl + Al*Bh per group
template<int T>
__device__ inline void gemm16ds(const u16* __restrict__ Ah0, const u16* __restrict__ Al0,
                                const u16* __restrict__ Ah1, const u16* __restrict__ Al1,
                                int lda, const u16* __restrict__ Bh, const u16* __restrict__ Bl,
                                int ct, int lane, f32x4 acc[2])
{
    const int r15 = lane & 15;
    const int koff = (lane >> 4) << 3;
    const int sx = (r15 & 7) << 3;
    constexpr int C = 2;
    static_assert(T % C == 0, "chunking");
#pragma unroll
    for (int b0 = 0; b0 < T; b0 += C){
        bf16x8 bh[C], bl[C], ah0[C], al0[C], ah1[C], al1[C];
#pragma unroll
        for (int c = 0; c < C; ++c){
            const int bo = (((b0 + c)*8 + ct)*64 + lane) << 3;
            bh[c] = *(const bf16x8*)(Bh + bo);
            bl[c] = *(const bf16x8*)(Bl + bo);
        }
#pragma unroll
        for (int c = 0; c < C; ++c){
            int kk = (((b0 + c) << 5) + koff) ^ sx;
            ah0[c] = *(const bf16x8*)(Ah0 + r15*lda + kk);
            al0[c] = *(const bf16x8*)(Al0 + r15*lda + kk);
            ah1[c] = *(const bf16x8*)(Ah1 + r15*lda + kk);
            al1[c] = *(const bf16x8*)(Al1 + r15*lda + kk);
        }
#pragma unroll
        for (int c = 0; c < C; ++c){
            acc[0] = MFMA(ah0[c], bh[c], acc[0], 0, 0, 0);
            acc[0] = MFMA(ah0[c], bl[c], acc[0], 0, 0, 0);
            acc[0] = MFMA(al0[c], bh[c], acc[0], 0, 0, 0);
            acc[1] = MFMA(ah1[c], bh[c], acc[1], 0, 0, 0);
            acc[1] = MFMA(ah1[c], bl[c], acc[1], 0, 0, 0);
            acc[1] = MFMA(al1[c], bh[c], acc[1], 0, 0, 0);
        }
    }
}

// epilogue (proven C/D mapping)
__device__ inline void epi16d(f32x4 acc[2], const float* __restrict__ bias,
                              int ct, int lane,
                              u16* D0hi, u16* D0lo, u16* D1hi, u16* D1lo)
{
    const int rr = (lane >> 4) << 2;
    const int col = ct*16 + (lane & 15);
    const float b = bias[col];
#pragma unroll
    for (int r = 0; r < 4; ++r){
        int m = rr + r;
        int idx = m*128 + (col ^ ((m & 7) << 3));
        float v0 = fmaxf(acc[0][r] + b, 0.f);
        float v1 = fmaxf(acc[1][r] + b, 0.f);
        u16 h0 = f2bfq(v0), h1 = f2bfq(v1);
        D0hi[idx] = h0;
        D1hi[idx] = h1;
        if (D0lo) D0lo[idx] = f2bfq(v0 - bf2f(h0));
        if (D1lo) D1lo[idx] = f2bfq(v1 - bf2f(h1));
    }
}

// ---------------- main fused kernel ----------------
__global__ __launch_bounds__(512, 6)
void rpe_mfma8(const int* __restrict__ aa, const int* __restrict__ res_nb,
               const int* __restrict__ chain_nb,
               const float* __restrict__ pos_atoms, const float* __restrict__ mask_atoms,
               const float* __restrict__ dist_b1, const float* __restrict__ dist_b2,
               const float* __restrict__ out_b1, const float* __restrict__ out_b2,
               const float* __restrict__ out_b3,
               const u16* __restrict__ ws, float* __restrict__ out)
{
    const int t  = threadIdx.x;
    const int g  = t >> 8;          // feature-phase group 0/1
    const int tl = t & 255;
    const int bid = blockIdx.x;     // 0..4095
    const int n  = bid >> 11;
    const int i  = (bid >> 3) & 255;
    const int j0b = (bid & 7) << 5; // block j-base (32 pairs)
    const int j0 = j0b + g*16;
    const int ri = n*L_SEQ + i;
    const int rj0 = n*L_SEQ + j0;

    __shared__ __align__(16) u16 s_g[2][TMP*264];    // gauss, lda 264 | L3+: h3h @0, h3l @2048 (lda128 swz)
    __shared__ __align__(16) u16 s_c1[2][TMP*264];   // aapair|relpos | L4+: h4h @0, h4l @2048
    __shared__ __align__(16) u16 s_c2[2][TMP*128];   // dist feat (XOR swz)
    __shared__ __align__(16) u16 s_c3[2][TMP*32];    // dihed, plain lda 32 (26 + pad)
    __shared__ __align__(16) u16 s_h1s[2][TMP*128];  // h1 (XOR swz); ALIASED with float4 staging
    __shared__ int   s_aapE[2][TMP];   // aap*256  (byte row offset, bf16 aa table)
    __shared__ int   s_aapS[2][TMP];   // aap*225  (f32 element row offset, sp table)
    __shared__ int   s_rpE[2][TMP];    // (same? rp:65)*256 byte row offset
    __shared__ float s_mpair[2][TMP];

    const float* sp_table = (const float*)(ws + WS_TOTAL);

    // float4 staging in dead h1 region: [16 res][15 atoms] {x,y,z,mask} + [15] for residue i
    float4* u_pm4  = (float4*)s_h1s[g];      // 240 * 16B = 3840 B
    float4* u_pmi4 = u_pm4 + 240;            // 15  * 16B -> total 4080 <= 4096 B

    // ---- stage residue data (per group), packed float4 ----
    if (tl < 240){
        int base = rj0*45 + tl*3;
        u_pm4[tl] = make_float4(pos_atoms[base], pos_atoms[base+1], pos_atoms[base+2],
                                mask_atoms[rj0*15 + tl]);
    } else if (tl < 255){
        int b = tl - 240;
        int base = ri*45 + b*3;
        u_pmi4[b] = make_float4(pos_atoms[base], pos_atoms[base+1], pos_atoms[base+2],
                                mask_atoms[ri*15 + b]);
    }
    if (tl < TMP){
        int m = tl, rj = rj0 + m;
        int aap = aa[ri]*22 + aa[rj];
        s_aapE[g][m] = aap << 8;        // *256 B
        s_aapS[g][m] = aap * 225;       // f32 elements
        int d = res_nb[ri] - res_nb[rj];
        d = min(max(d, -32), 32);
        bool same = (chain_nb[ri] == chain_nb[rj]);
        s_rpE[g][m] = (same ? (d + 32) : 65) << 8;
    }
    __syncthreads();   // B1: staging complete

    if (tl < TMP) s_mpair[g][tl] = u_pmi4[1].w * u_pm4[tl*15 + 1].w;   // BB_CA = 1

    // ---- gaussian distance features: k = tl fixed per thread, one b128 read per m ----
    {
        const int kg = tl;
        const bool act = kg < 225;
        if (act){
            int ga = kg / 15, gb = kg - ga*15;
            float4 pi = u_pmi4[ga];
#pragma unroll 4
            for (int m = 0; m < TMP; ++m){
                float4 pj = u_pm4[m*15 + gb];
                float dx = pi.x - pj.x;
                float dy = pi.y - pj.y;
                float dz = pi.z - pj.z;
                float d2 = fmaf(dz, dz, fmaf(dy, dy, fmaf(dx, dx, 1e-10f)));
                float c  = sp_table[s_aapS[g][m] + kg];          // already *0.01
                float gv = expf(-c*d2) * (pi.w * pj.w);
                s_g[g][m*264 + kg] = f2bfq(gv);
            }
        } else {
#pragma unroll
            for (int m = 0; m < TMP; ++m) s_g[g][m*264 + kg] = 0;   // zero cols 225..255
        }
    }

    // ---- embedding gathers: pure 16B copies from pre-converted bf16 tables ----
    {
        const u16* EA = ws + WS_EA;
        const u16* ER = ws + WS_ER;
#pragma unroll
        for (int it = 0; it < 2; ++it){
            int cid = tl + it*256;            // 0..511
            int m = cid >> 5, ch = cid & 31;  // 32 chunks of 8 u16 per row
            const u16* src = (ch < 16)
                ? (const u16*)((const char*)EA + s_aapE[g][m] + (ch << 4))
                : (const u16*)((const char*)ER + s_rpE[g][m] + ((ch - 16) << 4));
            *(bf16x8*)(s_c1[g] + m*264 + (ch << 3)) = *(const bf16x8*)src;
        }
    }

    // ---- dihedral features (plain lda-32 store) ----
    if (tl < 2*TMP){
        int m = tl >> 1, w = tl & 1;
        F3 P0, P1, P2, P3;
        float4 q0, q1, q2, q3;
        if (w == 0){   // phi: pC_i, pN_j, pCA_j, pC_j
            q0 = u_pmi4[2];       q1 = u_pm4[m*15 + 0];
            q2 = u_pm4[m*15 + 1]; q3 = u_pm4[m*15 + 2];
        } else {       // psi: pN_i, pCA_i, pC_i, pN_j
            q0 = u_pmi4[0];       q1 = u_pmi4[1];
            q2 = u_pmi4[2];       q3 = u_pm4[m*15 + 0];
        }
        P0 = {q0.x, q0.y, q0.z}; P1 = {q1.x, q1.y, q1.z};
        P2 = {q2.x, q2.y, q2.z}; P3 = {q3.x, q3.y, q3.z};
        float x = dihedral(P0, P1, P2, P3);
        u16* c3 = s_c3[g] + m*32 + w*13;
        c3[0]  = f2bfq(x);
        c3[1]  = f2bfq(sinf(x));
        c3[2]  = f2bfq(sinf(2.f*x));
        c3[3]  = f2bfq(sinf(3.f*x));
        c3[4]  = f2bfq(sinf(x));
        c3[5]  = f2bfq(sinf(0.5f*x));
        c3[6]  = f2bfq(sinf(x*(1.f/3.f)));
        c3[7]  = f2bfq(cosf(x));
        c3[8]  = f2bfq(cosf(2.f*x));
        c3[9]  = f2bfq(cosf(3.f*x));
        c3[10] = f2bfq(cosf(x));
        c3[11] = f2bfq(cosf(0.5f*x));
        c3[12] = f2bfq(cosf(x*(1.f/3.f)));
    }
    if (tl < TMP*6){ int m = tl/6; s_c3[g][m*32 + 26 + tl - m*6] = 0; }   // pad cols 26..31
    __syncthreads();   // B2: features complete (incl. all staging reads)

    const int lane = t & 63;
    const int w = t >> 6;          // wave -> ONE ct index (0..7), both groups

    u16* h3h0 = s_g[0];   u16* h3l0 = s_g[0]  + 2048;
    u16* h3h1 = s_g[1];   u16* h3l1 = s_g[1]  + 2048;
    u16* h4h0 = s_c1[0];  u16* h4l0 = s_c1[0] + 2048;
    u16* h4h1 = s_c1[1];  u16* h4l1 = s_c1[1] + 2048;

    // ---- L1: h1 = relu(g @ W1 + b1) ----
    f32x4 acc[2];
    acc[0] = {0,0,0,0}; acc[1] = {0,0,0,0};
    gemm16d<8,false>(s_g[0], s_g[1], 264, ws + WS_B1, w, lane, acc);
    epi16d(acc, dist_b1, w, lane, s_h1s[0], nullptr, s_h1s[1], nullptr);  // overwrites dead staging
    __syncthreads();   // B3

    // ---- L2: feat_dist = relu(h1 @ W2 + b2) ----
    acc[0] = {0,0,0,0}; acc[1] = {0,0,0,0};
    gemm16d<4,true>(s_h1s[0], s_h1s[1], 128, ws + WS_B2, w, lane, acc);
    epi16d(acc, dist_b2, w, lane, s_c2[0], nullptr, s_c2[1], nullptr);
    __syncthreads();   // B4

    // ---- L3: h3 = relu([c1|c2|c3] @ W3 + b3) -> hi+lo (aliases s_g) ----
    acc[0] = {0,0,0,0}; acc[1] = {0,0,0,0};
    gemm16d<8,false>(s_c1[0], s_c1[1], 264, ws + WS_B3,           w, lane, acc);
    gemm16d<4,true >(s_c2[0], s_c2[1], 128, ws + WS_B3 +  8*4096, w, lane, acc);
    gemm16d<1,false>(s_c3[0], s_c3[1],  32, ws + WS_B3 + 12*4096, w, lane, acc);
    epi16d(acc, out_b1, w, lane, h3h0, h3l0, h3h1, h3l1);
    __syncthreads();   // B5

    // ---- L4: h4 = relu(h3 @ W4 + b4) (split; aliases s_c1) ----
    acc[0] = {0,0,0,0}; acc[1] = {0,0,0,0};
    gemm16ds<4>(h3h0, h3l0, h3h1, h3l1, 128, ws + WS_B4, ws + WS_L4LO, w, lane, acc);
    epi16d(acc, out_b2, w, lane, h4h0, h4l0, h4h1, h4l1);
    __syncthreads();   // B6

    // ---- L5: out = (h4 @ W5 + b5) * mask_pair (split) ----
    acc[0] = {0,0,0,0}; acc[1] = {0,0,0,0};
    gemm16ds<4>(h4h0, h4l0, h4h1, h4l1, 128, ws + WS_B5, ws + WS_L5LO, w, lane, acc);
    {
        const int rr = (lane >> 4) << 2;
        const int col = w*16 + (lane & 15);
        const float b = out_b3[col];
#pragma unroll
        for (int gg = 0; gg < 2; ++gg){
            int jg = j0b + gg*16;
#pragma unroll
            for (int r = 0; r < 4; ++r){
                int m = rr + r;
                out[((size_t)(ri*L_SEQ) + (size_t)(jg + m))*128 + col] = (acc[gg][r] + b) * s_mpair[gg][m];
            }
        }
    }
}

extern "C" void kernel_launch(void* const* d_in, const int* in_sizes, int n_in,
                              void* d_out, int out_size, void* d_ws, size_t ws_size,
                              hipStream_t stream) {
    const int*   aa             = (const int*)  d_in[0];
    const int*   res_nb         = (const int*)  d_in[1];
    const int*   chain_nb       = (const int*)  d_in[2];
    const float* pos_atoms      = (const float*)d_in[3];
    const float* mask_atoms     = (const float*)d_in[4];
    const float* aa_embed_w     = (const float*)d_in[5];
    const float* relpos_embed_w = (const float*)d_in[6];
    const float* distcoef_w     = (const float*)d_in[7];
    const float* dist_w1        = (const float*)d_in[8];
    const float* dist_b1        = (const float*)d_in[9];
    const float* dist_w2        = (const float*)d_in[10];
    const float* dist_b2        = (const float*)d_in[11];
    const float* out_w1         = (const float*)d_in[12];
    const float* out_b1         = (const float*)d_in[13];
    const float* out_w2         = (const float*)d_in[14];
    const float* out_b2         = (const float*)d_in[15];
    const float* out_w3         = (const float*)d_in[16];
    const float* out_b3         = (const float*)d_in[17];
    float* out = (float*)d_out;
    u16* ws = (u16*)d_ws;

    hipLaunchKernelGGL(prep_w, dim3((WS_TOTAL + 255)/256), dim3(256), 0, stream,
                       dist_w1, dist_w2, out_w1, out_w2, out_w3, ws);
    hipLaunchKernelGGL(prep_t, dim3((SP_N + 255)/256), dim3(256), 0, stream,
                       distcoef_w, aa_embed_w, relpos_embed_w, ws);

    const int nblocks = 2 * L_SEQ * (L_SEQ / 32);   // 4096
    hipLaunchKernelGGL(rpe_mfma8, dim3(nblocks), dim3(512), 0, stream,
                       aa, res_nb, chain_nb, pos_atoms, mask_atoms,
                       dist_b1, dist_b2, out_b1, out_b2, out_b3,
                       ws, out);
}